// Round 5
// baseline (2697.773 us; speedup 1.0000x reference)
//
#include <hip/hip_runtime.h>
#include <hip/hip_bf16.h>

#define N_NODES 100000
#define S_SAMP 2
#define G_GRAPH 8
#define E_EDGES 400000
#define NLAYER 4
#define IN_CH 265
#define KPRE 288                      // 265 padded to mult of 96 (zero-filled)
#define NRT128 ((N_NODES + 127) / 128)  // 782 row tiles
#define NB1 ((N_NODES + 1023) / 1024)   // 98 scan blocks

typedef unsigned short u16;
typedef unsigned int u32;
typedef short bf16x8 __attribute__((ext_vector_type(8)));
typedef float f32x4 __attribute__((ext_vector_type(4)));

__device__ __forceinline__ float b2f(u16 u) {
    union { u32 i; float f; } x; x.i = ((u32)u) << 16; return x.f;
}
__device__ __forceinline__ u16 f2b(float f) {
    __hip_bfloat16 h = __float2bfloat16(f);
    return *reinterpret_cast<u16*>(&h);
}

// ---------------------------------------------------------------- features (per s)
__global__ void build_xin_k(const float* __restrict__ xf,
                            const float* __restrict__ dimf,
                            const float* __restrict__ layf,
                            const float* __restrict__ tilef,
                            const float* __restrict__ opemb,
                            const int* __restrict__ opcode,
                            const int* __restrict__ batch,
                            int s, u16* __restrict__ xin) {
    int n = blockIdx.x;
    int opc = opcode[n];
    int g = batch[n];
    u16* row = xin + (size_t)n * KPRE;
    for (int c = threadIdx.x; c < KPRE; c += blockDim.x) {
        float v = 0.0f;
        if (c < 53)       v = xf[(size_t)n * 53 + c];
        else if (c < 85)  v = opemb[opc * 32 + (c - 53)];
        else if (c < 223) v = dimf[(size_t)n * 138 + (c - 85)];
        else if (c < 247) v = layf[((size_t)n * S_SAMP + s) * 24 + (c - 223)];
        else if (c < 265) v = tilef[((size_t)g * S_SAMP + s) * 18 + (c - 247)];
        row[c] = f2b(v);
    }
}

// ---------------------------------------------------------------- weight packing (transposed)
// Wt: [L][512][256] bf16.  n<256 -> Wr_cat (X_next), n>=256 -> Wl_cat (H).
// Within each 256: col<128 = conv, col>=128 = rev.   bcat: [L][512] (upper 256 zero)
__global__ void pack_w_k(const float* __restrict__ cWl, const float* __restrict__ rWl,
                         const float* __restrict__ cWr, const float* __restrict__ rWr,
                         const float* __restrict__ cb,  const float* __restrict__ rb,
                         u16* __restrict__ Wt, float* __restrict__ bcat) {
    int idx = blockIdx.x * blockDim.x + threadIdx.x;   // L*512*256
    if (idx < NLAYER * 512 * 256) {
        int l = idx >> 17;
        int r = idx & 131071;
        int j = r >> 8;            // output col 0..511
        int k = r & 255;
        int jj = j & 255;
        int half = j >> 8;         // 0 = Wr, 1 = Wl
        int sub = jj >> 7;         // 0 = conv, 1 = rev
        int col = jj & 127;
        const float* src = half ? (sub ? rWl : cWl) : (sub ? rWr : cWr);
        Wt[idx] = f2b(src[((size_t)l * 256 + k) * 128 + col]);
    }
    if (idx < NLAYER * 512) {
        int l = idx >> 9;
        int j = idx & 511;
        float v = 0.0f;
        if (j < 256) v = (j < 128) ? cb[l * 128 + j] : rb[l * 128 + (j - 128)];
        bcat[idx] = v;
    }
}

// preWt: [256][KPRE] bf16 (transposed, zero-padded K)
__global__ void pack_pre_k(const float* __restrict__ preW, u16* __restrict__ preWt) {
    int idx = blockIdx.x * blockDim.x + threadIdx.x;
    if (idx >= 256 * KPRE) return;
    int j = idx / KPRE;
    int k = idx - j * KPRE;
    preWt[idx] = (k < IN_CH) ? f2b(preW[(size_t)k * 256 + j]) : (u16)0;
}

// ---------------------------------------------------------------- degrees + CSR
__global__ void deg_k(const int* __restrict__ ei, int* __restrict__ degF,
                      int* __restrict__ degR) {
    int e = blockIdx.x * blockDim.x + threadIdx.x;
    if (e < E_EDGES) {
        atomicAdd(&degF[ei[E_EDGES + e]], 1);
        atomicAdd(&degR[ei[e]], 1);
    }
}

__global__ __launch_bounds__(1024) void scan1_k(const int* __restrict__ degF,
                                                const int* __restrict__ degR,
                                                int* __restrict__ rpF,
                                                int* __restrict__ rpR,
                                                int* __restrict__ bsum) {
    const int* deg = blockIdx.y ? degR : degF;
    int* rp = blockIdx.y ? rpR : rpF;
    __shared__ int buf[1024];
    int i = blockIdx.x * 1024 + threadIdx.x;
    int v = (i < N_NODES) ? deg[i] : 0;
    buf[threadIdx.x] = v;
    __syncthreads();
    for (int off = 1; off < 1024; off <<= 1) {
        int t = (threadIdx.x >= off) ? buf[threadIdx.x - off] : 0;
        __syncthreads();
        buf[threadIdx.x] += t;
        __syncthreads();
    }
    if (i < N_NODES) rp[i] = buf[threadIdx.x] - v;
    if (threadIdx.x == 1023) bsum[blockIdx.y * NB1 + blockIdx.x] = buf[1023];
}

__global__ __launch_bounds__(256) void scan2_k(int* __restrict__ bsum,
                                               int* __restrict__ rpF,
                                               int* __restrict__ rpR) {
    __shared__ int buf[2][128];
    int half = threadIdx.x >> 7;
    int t = threadIdx.x & 127;
    int v = (t < NB1) ? bsum[half * NB1 + t] : 0;
    buf[half][t] = v;
    __syncthreads();
    for (int off = 1; off < 128; off <<= 1) {
        int x = (t >= off) ? buf[half][t - off] : 0;
        __syncthreads();
        buf[half][t] += x;
        __syncthreads();
    }
    if (t < NB1) bsum[half * NB1 + t] = buf[half][t] - v;
    if (t == NB1) (half ? rpR : rpF)[N_NODES] = buf[half][NB1 - 1];
}

__global__ void scan3_k(const int* __restrict__ bsum, int* __restrict__ rpF,
                        int* __restrict__ rpR) {
    int* rp = blockIdx.y ? rpR : rpF;
    int i = blockIdx.x * 1024 + threadIdx.x;
    if (i < N_NODES) rp[i] += bsum[blockIdx.y * NB1 + blockIdx.x];
}

__global__ void inv_cursor_k(const int* __restrict__ degF, const int* __restrict__ degR,
                             const int* __restrict__ rpF, const int* __restrict__ rpR,
                             float* __restrict__ invF, float* __restrict__ invR,
                             int* __restrict__ curF, int* __restrict__ curR) {
    int i = blockIdx.x * blockDim.x + threadIdx.x;
    if (i < N_NODES) {
        invF[i] = 1.0f / fmaxf((float)degF[i], 1.0f);
        invR[i] = 1.0f / fmaxf((float)degR[i], 1.0f);
        curF[i] = rpF[i];
        curR[i] = rpR[i];
    }
}

__global__ void fill_k(const int* __restrict__ ei, int* __restrict__ curF,
                       int* __restrict__ curR, int* __restrict__ colF,
                       int* __restrict__ colR) {
    int e = blockIdx.x * blockDim.x + threadIdx.x;
    if (e < E_EDGES) {
        int s = ei[e], t = ei[E_EDGES + e];
        colF[atomicAdd(&curF[t], 1)] = s;
        colR[atomicAdd(&curR[s], 1)] = t;
    }
}

// ---------------------------------------------------------------- MFMA GEMM
// C[M,N] = A[M,K] @ B[K,N] + bias (A already post-activation; optional relu on OUT).
// Bt[N][K] transposed weights. Block tile: 128 rows x 256 cols, 256 threads,
// 4 waves; wave w covers rows (w&1)*64..+64, cols (w>>1)*128..+128 (R=4, C=8).
// KC: compile-time K-chunk (mult of 32). Cols<256 of the GLOBAL N -> C0 (+bias),
// cols>=256 -> C1.
template <bool RELU_OUT, int KC>
__global__ __launch_bounds__(256) void mm2_k(const u16* __restrict__ A, int K, int M,
                                             const u16* __restrict__ Bt,
                                             const float* __restrict__ bias,
                                             u16* __restrict__ C0,
                                             u16* __restrict__ C1) {
    constexpr int KP = KC + 8;               // padded LDS stride (shorts)
    constexpr int CW = KC / 8;               // 16-byte chunks per row
    extern __shared__ u16 smem[];
    u16* As = smem;                          // [128][KP]
    u16* Bs = smem + 128 * KP;               // [256][KP]

    int tid = threadIdx.x;
    int colBase = blockIdx.x * 256;
    int rowBase = blockIdx.y * 128;
    int wv = tid >> 6, lane = tid & 63;
    int quad = lane >> 4, l16 = lane & 15;
    int rH = (wv & 1) * 64;
    int cH = (wv >> 1) * 128;

    f32x4 acc[4][8] = {};

    for (int k0 = 0; k0 < K; k0 += KC) {
        // stage A: 128 rows x KC
        #pragma unroll
        for (int it = 0; it < CW / 2; it++) {
            int v = tid + 256 * it;
            int r = v / CW;
            int kk = (v - r * CW) * 8;
            uint4 val = {0, 0, 0, 0};
            int row = rowBase + r;
            if (row < M) val = *(const uint4*)(A + (size_t)row * K + k0 + kk);
            *(uint4*)(As + r * KP + kk) = val;
        }
        // stage Bt: 256 cols x KC
        #pragma unroll
        for (int it = 0; it < CW; it++) {
            int v = tid + 256 * it;
            int r = v / CW;
            int kk = (v - r * CW) * 8;
            uint4 val = *(const uint4*)(Bt + (size_t)(colBase + r) * K + k0 + kk);
            *(uint4*)(Bs + r * KP + kk) = val;
        }
        __syncthreads();
        #pragma unroll
        for (int kk = 0; kk < KC; kk += 32) {
            bf16x8 af[4], bf[8];
            #pragma unroll
            for (int rf = 0; rf < 4; rf++)
                af[rf] = *(const bf16x8*)(As + (rH + rf * 16 + l16) * KP + kk + quad * 8);
            #pragma unroll
            for (int cf = 0; cf < 8; cf++)
                bf[cf] = *(const bf16x8*)(Bs + (cH + cf * 16 + l16) * KP + kk + quad * 8);
            #pragma unroll
            for (int rf = 0; rf < 4; rf++)
                #pragma unroll
                for (int cf = 0; cf < 8; cf++)
                    acc[rf][cf] = __builtin_amdgcn_mfma_f32_16x16x32_bf16(
                        af[rf], bf[cf], acc[rf][cf], 0, 0, 0);
        }
        __syncthreads();
    }

    // epilogue: C/D layout col=lane&15, row=quad*4+reg
    u16* dst = (colBase < 256) ? C0 : C1;
    #pragma unroll
    for (int cf = 0; cf < 8; cf++) {
        int col = cH + cf * 16 + l16;          // 0..255 within dst
        float bv = bias[colBase + col];
        #pragma unroll
        for (int rf = 0; rf < 4; rf++) {
            #pragma unroll
            for (int r = 0; r < 4; r++) {
                int row = rowBase + rH + rf * 16 + quad * 4 + r;
                if (row < M) {
                    float v = acc[rf][cf][r] + bv;
                    if (RELU_OUT) v = fmaxf(v, 0.0f);
                    dst[(size_t)row * 256 + col] = f2b(v);
                }
            }
        }
    }
}

// ---------------------------------------------------------------- aggregation (CSR gather)
// One wave per node. Lanes 0-31: fwd half (H[.,0:128]); lanes 32-63: rev half
// (H[.,128:256]). Each lane covers 4 shorts. X := relu(X + inv * gathered).
__global__ __launch_bounds__(256) void agg_k(const int* __restrict__ rpF,
                                             const int* __restrict__ colF,
                                             const int* __restrict__ rpR,
                                             const int* __restrict__ colR,
                                             const float* __restrict__ invF,
                                             const float* __restrict__ invR,
                                             const u16* __restrict__ H,
                                             u16* __restrict__ Xn) {
    int n = (blockIdx.x * blockDim.x + threadIdx.x) >> 6;
    if (n >= N_NODES) return;
    int lane = threadIdx.x & 63;
    int half = lane >> 5;
    int l32 = lane & 31;
    const int* rp  = half ? rpR : rpF;
    const int* col = half ? colR : colF;
    float inv = half ? invR[n] : invF[n];
    const u16* Hb = H + half * 128 + 4 * l32;

    float a0 = 0, a1 = 0, a2 = 0, a3 = 0;
    int b = rp[n], e = rp[n + 1];
    int j = b;
    for (; j + 3 < e; j += 4) {
        int c0 = col[j], c1 = col[j + 1], c2 = col[j + 2], c3 = col[j + 3];
        ushort4 h0 = *(const ushort4*)(Hb + (size_t)c0 * 256);
        ushort4 h1 = *(const ushort4*)(Hb + (size_t)c1 * 256);
        ushort4 h2 = *(const ushort4*)(Hb + (size_t)c2 * 256);
        ushort4 h3 = *(const ushort4*)(Hb + (size_t)c3 * 256);
        a0 += b2f(h0.x) + b2f(h1.x) + b2f(h2.x) + b2f(h3.x);
        a1 += b2f(h0.y) + b2f(h1.y) + b2f(h2.y) + b2f(h3.y);
        a2 += b2f(h0.z) + b2f(h1.z) + b2f(h2.z) + b2f(h3.z);
        a3 += b2f(h0.w) + b2f(h1.w) + b2f(h2.w) + b2f(h3.w);
    }
    for (; j < e; j++) {
        int c = col[j];
        ushort4 h = *(const ushort4*)(Hb + (size_t)c * 256);
        a0 += b2f(h.x); a1 += b2f(h.y); a2 += b2f(h.z); a3 += b2f(h.w);
    }
    u16* xp = Xn + (size_t)n * 256 + 4 * lane;
    ushort4 x = *(const ushort4*)xp;
    ushort4 o;
    o.x = f2b(fmaxf(b2f(x.x) + a0 * inv, 0.0f));
    o.y = f2b(fmaxf(b2f(x.y) + a1 * inv, 0.0f));
    o.z = f2b(fmaxf(b2f(x.z) + a2 * inv, 0.0f));
    o.w = f2b(fmaxf(b2f(x.w) + a3 * inv, 0.0f));
    *(ushort4*)xp = o;
}

// ---------------------------------------------------------------- pool + head
__global__ void out_init_k(float* __restrict__ out, const float* __restrict__ headb) {
    int i = threadIdx.x;
    if (i < G_GRAPH * S_SAMP) out[i] = headb[0];
}

// X stored post-relu: plain dot with headW slice.
__global__ __launch_bounds__(256) void pool_k(const u16* __restrict__ X,
                                              const float* __restrict__ headW, int woff,
                                              const int* __restrict__ batch,
                                              float* __restrict__ out, int s) {
    __shared__ float wsm[256];
    __shared__ float part[G_GRAPH];
    int tid = threadIdx.x;
    wsm[tid] = headW[woff + tid];
    if (tid < G_GRAPH) part[tid] = 0.0f;
    __syncthreads();
    int lane = tid & 63;
    int gw = blockIdx.x * 4 + (tid >> 6);
    int nw = gridDim.x * 4;
    for (int n = gw; n < N_NODES; n += nw) {
        const u16* p = X + (size_t)n * 256;
        float acc = 0.0f;
        #pragma unroll
        for (int j = 0; j < 4; j++) {
            int c = lane + 64 * j;
            acc += b2f(p[c]) * wsm[c];
        }
        #pragma unroll
        for (int off = 32; off > 0; off >>= 1) acc += __shfl_down(acc, off);
        if (lane == 0) atomicAdd(&part[batch[n]], acc);
    }
    __syncthreads();
    if (tid < G_GRAPH) atomicAdd(&out[tid * S_SAMP + s], part[tid]);
}

// ---------------------------------------------------------------- launch
extern "C" void kernel_launch(void* const* d_in, const int* in_sizes, int n_in,
                              void* d_out, int out_size, void* d_ws, size_t ws_size,
                              hipStream_t stream) {
    const float* x_feat      = (const float*)d_in[0];
    const float* dim_feat    = (const float*)d_in[1];
    const float* layout_feat = (const float*)d_in[2];
    const float* tile_feat   = (const float*)d_in[3];
    const float* opemb       = (const float*)d_in[4];
    const float* preW        = (const float*)d_in[5];
    const float* preb        = (const float*)d_in[6];
    const float* convWl      = (const float*)d_in[7];
    const float* convWr      = (const float*)d_in[8];
    const float* convb       = (const float*)d_in[9];
    const float* revWl       = (const float*)d_in[10];
    const float* revWr       = (const float*)d_in[11];
    const float* revb        = (const float*)d_in[12];
    const float* headW       = (const float*)d_in[13];
    const float* headb       = (const float*)d_in[14];
    const int*   node_opcode = (const int*)d_in[15];
    const int*   batch       = (const int*)d_in[16];
    const int*   edge_index  = (const int*)d_in[17];
    float* out = (float*)d_out;

    char* ws = (char*)d_ws;
    size_t off = 0;
    auto alloc = [&](size_t nbytes) {
        char* p = ws + off;
        off += (nbytes + 255) & ~(size_t)255;
        return p;
    };
    u16* XA    = (u16*)alloc((size_t)N_NODES * 256 * 2);
    u16* XB    = (u16*)alloc((size_t)N_NODES * 256 * 2);
    u16* XinH  = (u16*)alloc((size_t)N_NODES * KPRE * 2);  // Xin, then reused as H
    u16* Wt    = (u16*)alloc((size_t)NLAYER * 512 * 256 * 2);
    u16* preWt = (u16*)alloc((size_t)256 * KPRE * 2);
    float* bcat = (float*)alloc(NLAYER * 512 * 4);
    int* degF  = (int*)alloc(N_NODES * 4);
    int* degR  = (int*)alloc(N_NODES * 4);
    int* rpF   = (int*)alloc((N_NODES + 1) * 4);
    int* rpR   = (int*)alloc((N_NODES + 1) * 4);
    int* curF  = (int*)alloc(N_NODES * 4);
    int* curR  = (int*)alloc(N_NODES * 4);
    int* colF  = (int*)alloc(E_EDGES * 4);
    int* colR  = (int*)alloc(E_EDGES * 4);
    int* bsum  = (int*)alloc(2 * NB1 * 4);
    float* invF = (float*)alloc(N_NODES * 4);
    float* invR = (float*)alloc(N_NODES * 4);

    hipMemsetAsync(degF, 0, N_NODES * 4, stream);
    hipMemsetAsync(degR, 0, N_NODES * 4, stream);

    pack_w_k<<<(NLAYER * 512 * 256 + 255) / 256, 256, 0, stream>>>(
        convWl, revWl, convWr, revWr, convb, revb, Wt, bcat);
    pack_pre_k<<<(256 * KPRE + 255) / 256, 256, 0, stream>>>(preW, preWt);
    deg_k<<<(E_EDGES + 255) / 256, 256, 0, stream>>>(edge_index, degF, degR);
    scan1_k<<<dim3(NB1, 2), 1024, 0, stream>>>(degF, degR, rpF, rpR, bsum);
    scan2_k<<<1, 256, 0, stream>>>(bsum, rpF, rpR);
    scan3_k<<<dim3(NB1, 2), 1024, 0, stream>>>(bsum, rpF, rpR);
    inv_cursor_k<<<(N_NODES + 255) / 256, 256, 0, stream>>>(
        degF, degR, rpF, rpR, invF, invR, curF, curR);
    fill_k<<<(E_EDGES + 255) / 256, 256, 0, stream>>>(edge_index, curF, curR, colF, colR);

    out_init_k<<<1, 64, 0, stream>>>(out, headb);

    const int lds96 = (128 + 256) * (96 + 8) * 2;   // 79872 B
    const int lds64 = (128 + 256) * (64 + 8) * 2;   // 55296 B

    for (int s = 0; s < S_SAMP; s++) {
        build_xin_k<<<N_NODES, 256, 0, stream>>>(
            x_feat, dim_feat, layout_feat, tile_feat, opemb, node_opcode, batch, s, XinH);
        // X0 = relu(Xin @ preW + preb)  (stored POST-relu)
        mm2_k<true, 96><<<dim3(1, NRT128), 256, lds96, stream>>>(
            XinH, KPRE, N_NODES, preWt, preb, XA, XA);

        u16* ins[NLAYER]  = {XA, XB, XA, XB};
        u16* outs[NLAYER] = {XB, XA, XB, XA};
        for (int l = 0; l < NLAYER; l++) {
            // fused: [P | H] = x~ @ [Wr_cat | Wl_cat] + [b_cat | 0]  (no relu)
            mm2_k<false, 64><<<dim3(2, NRT128), 256, lds64, stream>>>(
                ins[l], 256, N_NODES, Wt + (size_t)l * 512 * 256,
                bcat + (size_t)l * 512, outs[l], XinH);
            // X_next~ = relu(P + inv-scaled gathered messages)
            agg_k<<<(N_NODES * 64 + 255) / 256, 256, 0, stream>>>(
                rpF, colF, rpR, colR, invF, invR, XinH, outs[l]);
            if (l == 2) pool_k<<<512, 256, 0, stream>>>(outs[l], headW, 0, batch, out, s);
            if (l == 3) pool_k<<<512, 256, 0, stream>>>(outs[l], headW, 256, batch, out, s);
        }
    }
}

// Round 6
// 1882.084 us; speedup vs baseline: 1.4334x; 1.4334x over previous
//
#include <hip/hip_runtime.h>
#include <hip/hip_bf16.h>

#define N_NODES 100000
#define S_SAMP 2
#define G_GRAPH 8
#define E_EDGES 400000
#define NLAYER 4
#define IN_CH 265
#define KPRE 288                        // 265 padded to mult of 96 (zero-filled)
#define NRT64 ((N_NODES + 63) / 64)     // 1563 row tiles
#define NGRP ((NRT64 + 7) / 8)          // 196 row-tile groups (8 per group -> 8 XCDs)
#define NB1 ((N_NODES + 1023) / 1024)   // 98 scan blocks

typedef unsigned short u16;
typedef unsigned int u32;
typedef short bf16x8 __attribute__((ext_vector_type(8)));
typedef float f32x4 __attribute__((ext_vector_type(4)));

__device__ __forceinline__ float b2f(u16 u) {
    union { u32 i; float f; } x; x.i = ((u32)u) << 16; return x.f;
}
__device__ __forceinline__ u16 f2b(float f) {
    __hip_bfloat16 h = __float2bfloat16(f);
    return *reinterpret_cast<u16*>(&h);
}

// ---------------------------------------------------------------- features (per s)
__global__ void build_xin_k(const float* __restrict__ xf,
                            const float* __restrict__ dimf,
                            const float* __restrict__ layf,
                            const float* __restrict__ tilef,
                            const float* __restrict__ opemb,
                            const int* __restrict__ opcode,
                            const int* __restrict__ batch,
                            int s, u16* __restrict__ xin) {
    int n = blockIdx.x;
    int opc = opcode[n];
    int g = batch[n];
    u16* row = xin + (size_t)n * KPRE;
    for (int c = threadIdx.x; c < KPRE; c += blockDim.x) {
        float v = 0.0f;
        if (c < 53)       v = xf[(size_t)n * 53 + c];
        else if (c < 85)  v = opemb[opc * 32 + (c - 53)];
        else if (c < 223) v = dimf[(size_t)n * 138 + (c - 85)];
        else if (c < 247) v = layf[((size_t)n * S_SAMP + s) * 24 + (c - 223)];
        else if (c < 265) v = tilef[((size_t)g * S_SAMP + s) * 18 + (c - 247)];
        row[c] = f2b(v);
    }
}

// ---------------------------------------------------------------- weight packing (transposed)
// Wt: [L][512][256] bf16.  n<256 -> Wr_cat (X_next), n>=256 -> Wl_cat (H).
// Within each 256: col<128 = conv, col>=128 = rev.   bcat: [L][512] (upper 256 zero)
__global__ void pack_w_k(const float* __restrict__ cWl, const float* __restrict__ rWl,
                         const float* __restrict__ cWr, const float* __restrict__ rWr,
                         const float* __restrict__ cb,  const float* __restrict__ rb,
                         u16* __restrict__ Wt, float* __restrict__ bcat) {
    int idx = blockIdx.x * blockDim.x + threadIdx.x;   // L*512*256
    if (idx < NLAYER * 512 * 256) {
        int l = idx >> 17;
        int r = idx & 131071;
        int j = r >> 8;            // output col 0..511
        int k = r & 255;
        int jj = j & 255;
        int half = j >> 8;         // 0 = Wr, 1 = Wl
        int sub = jj >> 7;         // 0 = conv, 1 = rev
        int col = jj & 127;
        const float* src = half ? (sub ? rWl : cWl) : (sub ? rWr : cWr);
        Wt[idx] = f2b(src[((size_t)l * 256 + k) * 128 + col]);
    }
    if (idx < NLAYER * 512) {
        int l = idx >> 9;
        int j = idx & 511;
        float v = 0.0f;
        if (j < 256) v = (j < 128) ? cb[l * 128 + j] : rb[l * 128 + (j - 128)];
        bcat[idx] = v;
    }
}

// preWt: [256][KPRE] bf16 (transposed, zero-padded K)
__global__ void pack_pre_k(const float* __restrict__ preW, u16* __restrict__ preWt) {
    int idx = blockIdx.x * blockDim.x + threadIdx.x;
    if (idx >= 256 * KPRE) return;
    int j = idx / KPRE;
    int k = idx - j * KPRE;
    preWt[idx] = (k < IN_CH) ? f2b(preW[(size_t)k * 256 + j]) : (u16)0;
}

// ---------------------------------------------------------------- degrees + CSR
__global__ void deg_k(const int* __restrict__ ei, int* __restrict__ degF,
                      int* __restrict__ degR) {
    int e = blockIdx.x * blockDim.x + threadIdx.x;
    if (e < E_EDGES) {
        atomicAdd(&degF[ei[E_EDGES + e]], 1);
        atomicAdd(&degR[ei[e]], 1);
    }
}

__global__ __launch_bounds__(1024) void scan1_k(const int* __restrict__ degF,
                                                const int* __restrict__ degR,
                                                int* __restrict__ rpF,
                                                int* __restrict__ rpR,
                                                int* __restrict__ bsum) {
    const int* deg = blockIdx.y ? degR : degF;
    int* rp = blockIdx.y ? rpR : rpF;
    __shared__ int buf[1024];
    int i = blockIdx.x * 1024 + threadIdx.x;
    int v = (i < N_NODES) ? deg[i] : 0;
    buf[threadIdx.x] = v;
    __syncthreads();
    for (int off = 1; off < 1024; off <<= 1) {
        int t = (threadIdx.x >= off) ? buf[threadIdx.x - off] : 0;
        __syncthreads();
        buf[threadIdx.x] += t;
        __syncthreads();
    }
    if (i < N_NODES) rp[i] = buf[threadIdx.x] - v;
    if (threadIdx.x == 1023) bsum[blockIdx.y * NB1 + blockIdx.x] = buf[1023];
}

__global__ __launch_bounds__(256) void scan2_k(int* __restrict__ bsum,
                                               int* __restrict__ rpF,
                                               int* __restrict__ rpR) {
    __shared__ int buf[2][128];
    int half = threadIdx.x >> 7;
    int t = threadIdx.x & 127;
    int v = (t < NB1) ? bsum[half * NB1 + t] : 0;
    buf[half][t] = v;
    __syncthreads();
    for (int off = 1; off < 128; off <<= 1) {
        int x = (t >= off) ? buf[half][t - off] : 0;
        __syncthreads();
        buf[half][t] += x;
        __syncthreads();
    }
    if (t < NB1) bsum[half * NB1 + t] = buf[half][t] - v;
    if (t == NB1) (half ? rpR : rpF)[N_NODES] = buf[half][NB1 - 1];
}

__global__ void scan3_k(const int* __restrict__ bsum, int* __restrict__ rpF,
                        int* __restrict__ rpR) {
    int* rp = blockIdx.y ? rpR : rpF;
    int i = blockIdx.x * 1024 + threadIdx.x;
    if (i < N_NODES) rp[i] += bsum[blockIdx.y * NB1 + blockIdx.x];
}

__global__ void inv_cursor_k(const int* __restrict__ degF, const int* __restrict__ degR,
                             const int* __restrict__ rpF, const int* __restrict__ rpR,
                             float* __restrict__ invF, float* __restrict__ invR,
                             int* __restrict__ curF, int* __restrict__ curR) {
    int i = blockIdx.x * blockDim.x + threadIdx.x;
    if (i < N_NODES) {
        invF[i] = 1.0f / fmaxf((float)degF[i], 1.0f);
        invR[i] = 1.0f / fmaxf((float)degR[i], 1.0f);
        curF[i] = rpF[i];
        curR[i] = rpR[i];
    }
}

__global__ void fill_k(const int* __restrict__ ei, int* __restrict__ curF,
                       int* __restrict__ curR, int* __restrict__ colF,
                       int* __restrict__ colR) {
    int e = blockIdx.x * blockDim.x + threadIdx.x;
    if (e < E_EDGES) {
        int s = ei[e], t = ei[E_EDGES + e];
        colF[atomicAdd(&curF[t], 1)] = s;
        colR[atomicAdd(&curR[s], 1)] = t;
    }
}

// ---------------------------------------------------------------- MFMA GEMM (64x64, XCD-swizzled)
// C[M,N] = A[M,K] @ B[K,N] + bias (A post-activation; optional relu on OUT).
// Bt[N][K] transposed weights. 64x64 tile, 256 thr, 4 waves; wave w = rows
// w*16..+16, all 64 cols. Grid 1D: bid = g*(8*COLT) + c*8 + x decodes to
// rowTile = g*8 + x, colTile = c -> all col-tiles of one row tile hit the
// SAME XCD (bid % 8 == x) back-to-back => A row-tile fetched once per chip.
// KC: compile-time K-chunk (mult of 32). Global col<256 -> C0 (+bias), else C1.
template <bool RELU_OUT, int KC, int COLT>
__global__ __launch_bounds__(256) void mm_sw_k(const u16* __restrict__ A, int K, int M,
                                               const u16* __restrict__ Bt,
                                               const float* __restrict__ bias,
                                               u16* __restrict__ C0,
                                               u16* __restrict__ C1) {
    constexpr int KP = KC + 8;             // padded LDS stride (shorts)
    __shared__ u16 As[64 * 136];
    __shared__ u16 Bs[64 * 136];
    static_assert(KP <= 136, "LDS stride overflow");

    int bid = blockIdx.x;
    int x = bid & 7;
    int q = bid >> 3;
    int c = q % COLT;
    int g = q / COLT;
    int rowTile = g * 8 + x;
    if (rowTile >= NRT64) return;
    int rowBase = rowTile * 64;
    int colBase = c * 64;

    int tid = threadIdx.x;
    int wave = tid >> 6;
    int lane = tid & 63;
    int quad = lane >> 4;
    int l16 = lane & 15;

    f32x4 acc[4] = {};
    constexpr int KC8 = KC >> 3;           // ushort8 chunks per row
    constexpr int NCH = 64 * KC8;

    for (int k0 = 0; k0 < K; k0 += KC) {
        // stage A chunk (64 rows x KC) — pure copy (A is post-activation)
        #pragma unroll
        for (int cc = tid; cc < NCH; cc += 256) {
            int r = cc / KC8;
            int kk = (cc - r * KC8) << 3;
            int row = rowBase + r;
            ushort4 a = {0, 0, 0, 0}, b = {0, 0, 0, 0};
            if (row < M) {
                const u16* p = A + (size_t)row * K + k0 + kk;
                a = ((const ushort4*)p)[0];
                b = ((const ushort4*)p)[1];
            }
            u16* d = As + r * KP + kk;
            ((ushort4*)d)[0] = a;
            ((ushort4*)d)[1] = b;
        }
        // stage Bt chunk (64 cols x KC)
        #pragma unroll
        for (int cc = tid; cc < NCH; cc += 256) {
            int r = cc / KC8;
            int kk = (cc - r * KC8) << 3;
            const u16* p = Bt + (size_t)(colBase + r) * K + k0 + kk;
            ushort4 a = ((const ushort4*)p)[0];
            ushort4 b = ((const ushort4*)p)[1];
            u16* d = Bs + r * KP + kk;
            ((ushort4*)d)[0] = a;
            ((ushort4*)d)[1] = b;
        }
        __syncthreads();
        #pragma unroll
        for (int k = 0; k < KC; k += 32) {
            bf16x8 af = *(const bf16x8*)(As + (wave * 16 + l16) * KP + k + quad * 8);
            #pragma unroll
            for (int cf = 0; cf < 4; cf++) {
                bf16x8 bf = *(const bf16x8*)(Bs + (cf * 16 + l16) * KP + k + quad * 8);
                acc[cf] = __builtin_amdgcn_mfma_f32_16x16x32_bf16(af, bf, acc[cf], 0, 0, 0);
            }
        }
        __syncthreads();
    }

    // epilogue: C/D layout col=lane&15, row=quad*4+reg
    u16* dst = (colBase < 256) ? C0 : C1;
    int cb = colBase & 255;
    #pragma unroll
    for (int cf = 0; cf < 4; cf++) {
        int col = cb + cf * 16 + l16;
        float bv = bias[colBase + cf * 16 + l16];
        #pragma unroll
        for (int r = 0; r < 4; r++) {
            int row = rowBase + wave * 16 + quad * 4 + r;
            if (row < M) {
                float v = acc[cf][r] + bv;
                if (RELU_OUT) v = fmaxf(v, 0.0f);
                dst[(size_t)row * 256 + col] = f2b(v);
            }
        }
    }
}

// ---------------------------------------------------------------- aggregation (CSR gather)
// One wave per node. Lanes 0-31: fwd half (H[.,0:128]); lanes 32-63: rev half
// (H[.,128:256]). Each lane covers 4 shorts. X := relu(X + inv * gathered).
__global__ __launch_bounds__(256) void agg_k(const int* __restrict__ rpF,
                                             const int* __restrict__ colF,
                                             const int* __restrict__ rpR,
                                             const int* __restrict__ colR,
                                             const float* __restrict__ invF,
                                             const float* __restrict__ invR,
                                             const u16* __restrict__ H,
                                             u16* __restrict__ Xn) {
    int n = (blockIdx.x * blockDim.x + threadIdx.x) >> 6;
    if (n >= N_NODES) return;
    int lane = threadIdx.x & 63;
    int half = lane >> 5;
    int l32 = lane & 31;
    const int* rp  = half ? rpR : rpF;
    const int* col = half ? colR : colF;
    float inv = half ? invR[n] : invF[n];
    const u16* Hb = H + half * 128 + 4 * l32;

    float a0 = 0, a1 = 0, a2 = 0, a3 = 0;
    int b = rp[n], e = rp[n + 1];
    int j = b;
    for (; j + 3 < e; j += 4) {
        int c0 = col[j], c1 = col[j + 1], c2 = col[j + 2], c3 = col[j + 3];
        ushort4 h0 = *(const ushort4*)(Hb + (size_t)c0 * 256);
        ushort4 h1 = *(const ushort4*)(Hb + (size_t)c1 * 256);
        ushort4 h2 = *(const ushort4*)(Hb + (size_t)c2 * 256);
        ushort4 h3 = *(const ushort4*)(Hb + (size_t)c3 * 256);
        a0 += b2f(h0.x) + b2f(h1.x) + b2f(h2.x) + b2f(h3.x);
        a1 += b2f(h0.y) + b2f(h1.y) + b2f(h2.y) + b2f(h3.y);
        a2 += b2f(h0.z) + b2f(h1.z) + b2f(h2.z) + b2f(h3.z);
        a3 += b2f(h0.w) + b2f(h1.w) + b2f(h2.w) + b2f(h3.w);
    }
    for (; j < e; j++) {
        int c = col[j];
        ushort4 h = *(const ushort4*)(Hb + (size_t)c * 256);
        a0 += b2f(h.x); a1 += b2f(h.y); a2 += b2f(h.z); a3 += b2f(h.w);
    }
    u16* xp = Xn + (size_t)n * 256 + 4 * lane;
    ushort4 xv = *(const ushort4*)xp;
    ushort4 o;
    o.x = f2b(fmaxf(b2f(xv.x) + a0 * inv, 0.0f));
    o.y = f2b(fmaxf(b2f(xv.y) + a1 * inv, 0.0f));
    o.z = f2b(fmaxf(b2f(xv.z) + a2 * inv, 0.0f));
    o.w = f2b(fmaxf(b2f(xv.w) + a3 * inv, 0.0f));
    *(ushort4*)xp = o;
}

// ---------------------------------------------------------------- pool + head
__global__ void out_init_k(float* __restrict__ out, const float* __restrict__ headb) {
    int i = threadIdx.x;
    if (i < G_GRAPH * S_SAMP) out[i] = headb[0];
}

// X stored post-relu: plain dot with headW slice.
__global__ __launch_bounds__(256) void pool_k(const u16* __restrict__ X,
                                              const float* __restrict__ headW, int woff,
                                              const int* __restrict__ batch,
                                              float* __restrict__ out, int s) {
    __shared__ float wsm[256];
    __shared__ float part[G_GRAPH];
    int tid = threadIdx.x;
    wsm[tid] = headW[woff + tid];
    if (tid < G_GRAPH) part[tid] = 0.0f;
    __syncthreads();
    int lane = tid & 63;
    int gw = blockIdx.x * 4 + (tid >> 6);
    int nw = gridDim.x * 4;
    for (int n = gw; n < N_NODES; n += nw) {
        const u16* p = X + (size_t)n * 256;
        float acc = 0.0f;
        #pragma unroll
        for (int j = 0; j < 4; j++) {
            int c = lane + 64 * j;
            acc += b2f(p[c]) * wsm[c];
        }
        #pragma unroll
        for (int off = 32; off > 0; off >>= 1) acc += __shfl_down(acc, off);
        if (lane == 0) atomicAdd(&part[batch[n]], acc);
    }
    __syncthreads();
    if (tid < G_GRAPH) atomicAdd(&out[tid * S_SAMP + s], part[tid]);
}

// ---------------------------------------------------------------- launch
extern "C" void kernel_launch(void* const* d_in, const int* in_sizes, int n_in,
                              void* d_out, int out_size, void* d_ws, size_t ws_size,
                              hipStream_t stream) {
    const float* x_feat      = (const float*)d_in[0];
    const float* dim_feat    = (const float*)d_in[1];
    const float* layout_feat = (const float*)d_in[2];
    const float* tile_feat   = (const float*)d_in[3];
    const float* opemb       = (const float*)d_in[4];
    const float* preW        = (const float*)d_in[5];
    const float* preb        = (const float*)d_in[6];
    const float* convWl      = (const float*)d_in[7];
    const float* convWr      = (const float*)d_in[8];
    const float* convb       = (const float*)d_in[9];
    const float* revWl       = (const float*)d_in[10];
    const float* revWr       = (const float*)d_in[11];
    const float* revb        = (const float*)d_in[12];
    const float* headW       = (const float*)d_in[13];
    const float* headb       = (const float*)d_in[14];
    const int*   node_opcode = (const int*)d_in[15];
    const int*   batch       = (const int*)d_in[16];
    const int*   edge_index  = (const int*)d_in[17];
    float* out = (float*)d_out;

    char* ws = (char*)d_ws;
    size_t off = 0;
    auto alloc = [&](size_t nbytes) {
        char* p = ws + off;
        off += (nbytes + 255) & ~(size_t)255;
        return p;
    };
    u16* XA    = (u16*)alloc((size_t)N_NODES * 256 * 2);
    u16* XB    = (u16*)alloc((size_t)N_NODES * 256 * 2);
    u16* XinH  = (u16*)alloc((size_t)N_NODES * KPRE * 2);  // Xin, then reused as H
    u16* Wt    = (u16*)alloc((size_t)NLAYER * 512 * 256 * 2);
    u16* preWt = (u16*)alloc((size_t)256 * KPRE * 2);
    float* bcat = (float*)alloc(NLAYER * 512 * 4);
    int* degF  = (int*)alloc(N_NODES * 4);
    int* degR  = (int*)alloc(N_NODES * 4);
    int* rpF   = (int*)alloc((N_NODES + 1) * 4);
    int* rpR   = (int*)alloc((N_NODES + 1) * 4);
    int* curF  = (int*)alloc(N_NODES * 4);
    int* curR  = (int*)alloc(N_NODES * 4);
    int* colF  = (int*)alloc(E_EDGES * 4);
    int* colR  = (int*)alloc(E_EDGES * 4);
    int* bsum  = (int*)alloc(2 * NB1 * 4);
    float* invF = (float*)alloc(N_NODES * 4);
    float* invR = (float*)alloc(N_NODES * 4);

    hipMemsetAsync(degF, 0, N_NODES * 4, stream);
    hipMemsetAsync(degR, 0, N_NODES * 4, stream);

    pack_w_k<<<(NLAYER * 512 * 256 + 255) / 256, 256, 0, stream>>>(
        convWl, revWl, convWr, revWr, convb, revb, Wt, bcat);
    pack_pre_k<<<(256 * KPRE + 255) / 256, 256, 0, stream>>>(preW, preWt);
    deg_k<<<(E_EDGES + 255) / 256, 256, 0, stream>>>(edge_index, degF, degR);
    scan1_k<<<dim3(NB1, 2), 1024, 0, stream>>>(degF, degR, rpF, rpR, bsum);
    scan2_k<<<1, 256, 0, stream>>>(bsum, rpF, rpR);
    scan3_k<<<dim3(NB1, 2), 1024, 0, stream>>>(bsum, rpF, rpR);
    inv_cursor_k<<<(N_NODES + 255) / 256, 256, 0, stream>>>(
        degF, degR, rpF, rpR, invF, invR, curF, curR);
    fill_k<<<(E_EDGES + 255) / 256, 256, 0, stream>>>(edge_index, curF, curR, colF, colR);

    out_init_k<<<1, 64, 0, stream>>>(out, headb);

    for (int s = 0; s < S_SAMP; s++) {
        build_xin_k<<<N_NODES, 256, 0, stream>>>(
            x_feat, dim_feat, layout_feat, tile_feat, opemb, node_opcode, batch, s, XinH);
        // X0 = relu(Xin @ preW + preb)  (stored POST-relu); KC=96, 4 col tiles
        mm_sw_k<true, 96, 4><<<NGRP * 8 * 4, 256, 0, stream>>>(
            XinH, KPRE, N_NODES, preWt, preb, XA, XA);

        u16* ins[NLAYER]  = {XA, XB, XA, XB};
        u16* outs[NLAYER] = {XB, XA, XB, XA};
        for (int l = 0; l < NLAYER; l++) {
            // fused: [P | H] = x~ @ [Wr_cat | Wl_cat] + [b_cat | 0]  (no relu)
            mm_sw_k<false, 128, 8><<<NGRP * 8 * 8, 256, 0, stream>>>(
                ins[l], 256, N_NODES, Wt + (size_t)l * 512 * 256,
                bcat + (size_t)l * 512, outs[l], XinH);
            // X_next~ = relu(P + inv-scaled gathered messages)
            agg_k<<<(N_NODES * 64 + 255) / 256, 256, 0, stream>>>(
                rpF, colF, rpR, colR, invF, invR, XinH, outs[l]);
            if (l == 2) pool_k<<<512, 256, 0, stream>>>(outs[l], headW, 0, batch, out, s);
            if (l == 3) pool_k<<<512, 256, 0, stream>>>(outs[l], headW, 256, batch, out, s);
        }
    }
}

// Round 7
// 1811.620 us; speedup vs baseline: 1.4891x; 1.0389x over previous
//
#include <hip/hip_runtime.h>
#include <hip/hip_bf16.h>

#define N_NODES 100000
#define S_SAMP 2
#define G_GRAPH 8
#define E_EDGES 400000
#define NLAYER 4
#define IN_CH 265
#define KPRE 288                        // 265 padded to mult of 96 (zero-filled)
#define NRT64 ((N_NODES + 63) / 64)     // 1563 row tiles
#define NPAD (NRT64 * 64)               // 100032 padded rows for X buffers
#define NGRP ((NRT64 + 7) / 8)          // 196 row-tile groups (8 -> 8 XCDs)
#define NB1 ((N_NODES + 1023) / 1024)   // 98 scan blocks

typedef unsigned short u16;
typedef unsigned int u32;
typedef short bf16x8 __attribute__((ext_vector_type(8)));
typedef float f32x4 __attribute__((ext_vector_type(4)));

__device__ __forceinline__ float b2f(u16 u) {
    union { u32 i; float f; } x; x.i = ((u32)u) << 16; return x.f;
}
__device__ __forceinline__ u16 f2b(float f) {
    __hip_bfloat16 h = __float2bfloat16(f);
    return *reinterpret_cast<u16*>(&h);
}

// async global->LDS, 16B per lane; lds dest = wave-uniform base + lane*16
__device__ __forceinline__ void gl_lds16(const u16* g, u16* l) {
    __builtin_amdgcn_global_load_lds(
        (const __attribute__((address_space(1))) void*)g,
        (__attribute__((address_space(3))) void*)l, 16, 0, 0);
}

// ---------------------------------------------------------------- features (per s)
__global__ void build_xin_k(const float* __restrict__ xf,
                            const float* __restrict__ dimf,
                            const float* __restrict__ layf,
                            const float* __restrict__ tilef,
                            const float* __restrict__ opemb,
                            const int* __restrict__ opcode,
                            const int* __restrict__ batch,
                            int s, u16* __restrict__ xin) {
    int n = blockIdx.x;
    int opc = opcode[n];
    int g = batch[n];
    u16* row = xin + (size_t)n * KPRE;
    for (int c = threadIdx.x; c < KPRE; c += blockDim.x) {
        float v = 0.0f;
        if (c < 53)       v = xf[(size_t)n * 53 + c];
        else if (c < 85)  v = opemb[opc * 32 + (c - 53)];
        else if (c < 223) v = dimf[(size_t)n * 138 + (c - 85)];
        else if (c < 247) v = layf[((size_t)n * S_SAMP + s) * 24 + (c - 223)];
        else if (c < 265) v = tilef[((size_t)g * S_SAMP + s) * 18 + (c - 247)];
        row[c] = f2b(v);
    }
}

// ---------------------------------------------------------------- weight packing (transposed)
// Wt: [L][512][256] bf16.  n<256 -> Wr_cat (X_next), n>=256 -> Wl_cat (H).
// Within each 256: col<128 = conv, col>=128 = rev.   bcat: [L][512] (upper 256 zero)
__global__ void pack_w_k(const float* __restrict__ cWl, const float* __restrict__ rWl,
                         const float* __restrict__ cWr, const float* __restrict__ rWr,
                         const float* __restrict__ cb,  const float* __restrict__ rb,
                         u16* __restrict__ Wt, float* __restrict__ bcat) {
    int idx = blockIdx.x * blockDim.x + threadIdx.x;   // L*512*256
    if (idx < NLAYER * 512 * 256) {
        int l = idx >> 17;
        int r = idx & 131071;
        int j = r >> 8;            // output col 0..511
        int k = r & 255;
        int jj = j & 255;
        int half = j >> 8;         // 0 = Wr, 1 = Wl
        int sub = jj >> 7;         // 0 = conv, 1 = rev
        int col = jj & 127;
        const float* src = half ? (sub ? rWl : cWl) : (sub ? rWr : cWr);
        Wt[idx] = f2b(src[((size_t)l * 256 + k) * 128 + col]);
    }
    if (idx < NLAYER * 512) {
        int l = idx >> 9;
        int j = idx & 511;
        float v = 0.0f;
        if (j < 256) v = (j < 128) ? cb[l * 128 + j] : rb[l * 128 + (j - 128)];
        bcat[idx] = v;
    }
}

// preWt: [256][KPRE] bf16 (transposed, zero-padded K)
__global__ void pack_pre_k(const float* __restrict__ preW, u16* __restrict__ preWt) {
    int idx = blockIdx.x * blockDim.x + threadIdx.x;
    if (idx >= 256 * KPRE) return;
    int j = idx / KPRE;
    int k = idx - j * KPRE;
    preWt[idx] = (k < IN_CH) ? f2b(preW[(size_t)k * 256 + j]) : (u16)0;
}

// ---------------------------------------------------------------- degrees + CSR
__global__ void deg_k(const int* __restrict__ ei, int* __restrict__ degF,
                      int* __restrict__ degR) {
    int e = blockIdx.x * blockDim.x + threadIdx.x;
    if (e < E_EDGES) {
        atomicAdd(&degF[ei[E_EDGES + e]], 1);
        atomicAdd(&degR[ei[e]], 1);
    }
}

__global__ __launch_bounds__(1024) void scan1_k(const int* __restrict__ degF,
                                                const int* __restrict__ degR,
                                                int* __restrict__ rpF,
                                                int* __restrict__ rpR,
                                                int* __restrict__ bsum) {
    const int* deg = blockIdx.y ? degR : degF;
    int* rp = blockIdx.y ? rpR : rpF;
    __shared__ int buf[1024];
    int i = blockIdx.x * 1024 + threadIdx.x;
    int v = (i < N_NODES) ? deg[i] : 0;
    buf[threadIdx.x] = v;
    __syncthreads();
    for (int off = 1; off < 1024; off <<= 1) {
        int t = (threadIdx.x >= off) ? buf[threadIdx.x - off] : 0;
        __syncthreads();
        buf[threadIdx.x] += t;
        __syncthreads();
    }
    if (i < N_NODES) rp[i] = buf[threadIdx.x] - v;
    if (threadIdx.x == 1023) bsum[blockIdx.y * NB1 + blockIdx.x] = buf[1023];
}

__global__ __launch_bounds__(256) void scan2_k(int* __restrict__ bsum,
                                               int* __restrict__ rpF,
                                               int* __restrict__ rpR) {
    __shared__ int buf[2][128];
    int half = threadIdx.x >> 7;
    int t = threadIdx.x & 127;
    int v = (t < NB1) ? bsum[half * NB1 + t] : 0;
    buf[half][t] = v;
    __syncthreads();
    for (int off = 1; off < 128; off <<= 1) {
        int x = (t >= off) ? buf[half][t - off] : 0;
        __syncthreads();
        buf[half][t] += x;
        __syncthreads();
    }
    if (t < NB1) bsum[half * NB1 + t] = buf[half][t] - v;
    if (t == NB1) (half ? rpR : rpF)[N_NODES] = buf[half][NB1 - 1];
}

__global__ void scan3_k(const int* __restrict__ bsum, int* __restrict__ rpF,
                        int* __restrict__ rpR) {
    int* rp = blockIdx.y ? rpR : rpF;
    int i = blockIdx.x * 1024 + threadIdx.x;
    if (i < N_NODES) rp[i] += bsum[blockIdx.y * NB1 + blockIdx.x];
}

__global__ void inv_cursor_k(const int* __restrict__ degF, const int* __restrict__ degR,
                             const int* __restrict__ rpF, const int* __restrict__ rpR,
                             float* __restrict__ invF, float* __restrict__ invR,
                             int* __restrict__ curF, int* __restrict__ curR) {
    int i = blockIdx.x * blockDim.x + threadIdx.x;
    if (i < N_NODES) {
        invF[i] = 1.0f / fmaxf((float)degF[i], 1.0f);
        invR[i] = 1.0f / fmaxf((float)degR[i], 1.0f);
        curF[i] = rpF[i];
        curR[i] = rpR[i];
    }
}

__global__ void fill_k(const int* __restrict__ ei, int* __restrict__ curF,
                       int* __restrict__ curR, int* __restrict__ colF,
                       int* __restrict__ colR) {
    int e = blockIdx.x * blockDim.x + threadIdx.x;
    if (e < E_EDGES) {
        int s = ei[e], t = ei[E_EDGES + e];
        colF[atomicAdd(&curF[t], 1)] = s;
        colR[atomicAdd(&curR[s], 1)] = t;
    }
}

// ---------------------------------------------------------------- layer GEMM (K=256, async-staged)
// [P|H](row, :) = A[row,0:256] @ Bt^T + bias.  64x64 tile, 256 thr, 4 waves.
// Full K staged once via global_load_lds (16B/lane), XOR chunk swizzle
// (slot = chunk ^ (row&31)) keeps staging contiguous AND frag reads 2-way-free.
// One __syncthreads per block. XCD swizzle: bid = g*64 + c*8 + x.
__global__ __launch_bounds__(256) void mmL_k(const u16* __restrict__ A,
                                             const u16* __restrict__ Bt,
                                             const float* __restrict__ bias,
                                             u16* __restrict__ P,
                                             u16* __restrict__ H) {
    __shared__ u16 As[64 * 256];
    __shared__ u16 Bs[64 * 256];

    int bid = blockIdx.x;
    int x = bid & 7;
    int q = bid >> 3;
    int c = q & 7;                      // col tile 0..7 (COLT=8)
    int g = q >> 3;
    int rowTile = g * 8 + x;
    if (rowTile >= NRT64) return;
    int rowBase = rowTile * 64;
    int colBase = c * 64;

    int tid = threadIdx.x;
    int wv = tid >> 6;
    int lane = tid & 63;
    int quad = lane >> 4;
    int l16 = lane & 15;

    // stage: wave wv covers rows [wv*16, wv*16+16) of both tiles.
    // instr i writes 2 rows (64 slots); lane l -> row +=(l>>5), slot l&31.
    {
        int rsub = (lane >> 5);
        int sl = lane & 31;
        #pragma unroll
        for (int i = 0; i < 8; i++) {
            int r = wv * 16 + 2 * i + rsub;
            int ch = sl ^ (r & 31);
            gl_lds16(A + (size_t)(rowBase + r) * 256 + ch * 8,
                     As + (wv * 16 + 2 * i) * 256);
        }
        #pragma unroll
        for (int i = 0; i < 8; i++) {
            int r = wv * 16 + 2 * i + rsub;
            int ch = sl ^ (r & 31);
            gl_lds16(Bt + (size_t)(colBase + r) * 256 + ch * 8,
                     Bs + (wv * 16 + 2 * i) * 256);
        }
    }
    __syncthreads();   // compiler emits vmcnt(0) drain before barrier

    f32x4 acc[4] = {};
    int ra = wv * 16 + l16;            // A row this lane reads
    #pragma unroll
    for (int ks = 0; ks < 8; ks++) {
        int ca = ks * 4 + quad;
        bf16x8 af = *(const bf16x8*)(As + ra * 256 + (ca ^ (ra & 31)) * 8);
        #pragma unroll
        for (int cf = 0; cf < 4; cf++) {
            int rb = cf * 16 + l16;
            bf16x8 bf = *(const bf16x8*)(Bs + rb * 256 + (ca ^ (rb & 31)) * 8);
            acc[cf] = __builtin_amdgcn_mfma_f32_16x16x32_bf16(af, bf, acc[cf], 0, 0, 0);
        }
    }

    // epilogue: C/D layout col=lane&15, row=quad*4+reg
    u16* dst = (colBase < 256) ? P : H;
    int cb = colBase & 255;
    #pragma unroll
    for (int cf = 0; cf < 4; cf++) {
        int col = cb + cf * 16 + l16;
        float bv = bias[colBase + cf * 16 + l16];
        #pragma unroll
        for (int r = 0; r < 4; r++) {
            int row = rowBase + wv * 16 + quad * 4 + r;
            if (row < N_NODES) dst[(size_t)row * 256 + col] = f2b(acc[cf][r] + bv);
        }
    }
}

// ---------------------------------------------------------------- pre-GEMM (K=288, classic staging)
template <bool RELU_OUT, int KC, int COLT>
__global__ __launch_bounds__(256) void mm_sw_k(const u16* __restrict__ A, int K, int M,
                                               const u16* __restrict__ Bt,
                                               const float* __restrict__ bias,
                                               u16* __restrict__ C0) {
    constexpr int KP = KC + 8;
    __shared__ u16 As[64 * 136];
    __shared__ u16 Bs[64 * 136];
    static_assert(KP <= 136, "LDS stride overflow");

    int bid = blockIdx.x;
    int x = bid & 7;
    int q = bid >> 3;
    int c = q % COLT;
    int g = q / COLT;
    int rowTile = g * 8 + x;
    if (rowTile >= NRT64) return;
    int rowBase = rowTile * 64;
    int colBase = c * 64;

    int tid = threadIdx.x;
    int wave = tid >> 6;
    int lane = tid & 63;
    int quad = lane >> 4;
    int l16 = lane & 15;

    f32x4 acc[4] = {};
    constexpr int KC8 = KC >> 3;
    constexpr int NCH = 64 * KC8;

    for (int k0 = 0; k0 < K; k0 += KC) {
        #pragma unroll
        for (int cc = tid; cc < NCH; cc += 256) {
            int r = cc / KC8;
            int kk = (cc - r * KC8) << 3;
            int row = rowBase + r;
            ushort4 a = {0, 0, 0, 0}, b = {0, 0, 0, 0};
            if (row < M) {
                const u16* p = A + (size_t)row * K + k0 + kk;
                a = ((const ushort4*)p)[0];
                b = ((const ushort4*)p)[1];
            }
            u16* d = As + r * KP + kk;
            ((ushort4*)d)[0] = a;
            ((ushort4*)d)[1] = b;
        }
        #pragma unroll
        for (int cc = tid; cc < NCH; cc += 256) {
            int r = cc / KC8;
            int kk = (cc - r * KC8) << 3;
            const u16* p = Bt + (size_t)(colBase + r) * K + k0 + kk;
            ushort4 a = ((const ushort4*)p)[0];
            ushort4 b = ((const ushort4*)p)[1];
            u16* d = Bs + r * KP + kk;
            ((ushort4*)d)[0] = a;
            ((ushort4*)d)[1] = b;
        }
        __syncthreads();
        #pragma unroll
        for (int k = 0; k < KC; k += 32) {
            bf16x8 af = *(const bf16x8*)(As + (wave * 16 + l16) * KP + k + quad * 8);
            #pragma unroll
            for (int cf = 0; cf < 4; cf++) {
                bf16x8 bf = *(const bf16x8*)(Bs + (cf * 16 + l16) * KP + k + quad * 8);
                acc[cf] = __builtin_amdgcn_mfma_f32_16x16x32_bf16(af, bf, acc[cf], 0, 0, 0);
            }
        }
        __syncthreads();
    }

    #pragma unroll
    for (int cf = 0; cf < 4; cf++) {
        int col = colBase + cf * 16 + l16;
        float bv = bias[col];
        #pragma unroll
        for (int r = 0; r < 4; r++) {
            int row = rowBase + wave * 16 + quad * 4 + r;
            if (row < M) {
                float v = acc[cf][r] + bv;
                if (RELU_OUT) v = fmaxf(v, 0.0f);
                C0[(size_t)row * 256 + col] = f2b(v);
            }
        }
    }
}

// ---------------------------------------------------------------- aggregation (CSR gather)
// One wave per node. Lanes 0-31: fwd half (H[.,0:128]); lanes 32-63: rev half.
// X := relu(X + inv * gathered). If DOT: also dotbuf[n] = X_new . w (w = headW slice).
template <bool DOT>
__global__ __launch_bounds__(256) void agg_k(const int* __restrict__ rpF,
                                             const int* __restrict__ colF,
                                             const int* __restrict__ rpR,
                                             const int* __restrict__ colR,
                                             const float* __restrict__ invF,
                                             const float* __restrict__ invR,
                                             const u16* __restrict__ H,
                                             u16* __restrict__ Xn,
                                             const float* __restrict__ w,
                                             float* __restrict__ dotbuf) {
    int n = (blockIdx.x * blockDim.x + threadIdx.x) >> 6;
    if (n >= N_NODES) return;
    int lane = threadIdx.x & 63;
    int half = lane >> 5;
    int l32 = lane & 31;
    const int* rp  = half ? rpR : rpF;
    const int* col = half ? colR : colF;
    float inv = half ? invR[n] : invF[n];
    const u16* Hb = H + half * 128 + 4 * l32;

    float a0 = 0, a1 = 0, a2 = 0, a3 = 0;
    int b = rp[n], e = rp[n + 1];
    int j = b;
    for (; j + 3 < e; j += 4) {
        int c0 = col[j], c1 = col[j + 1], c2 = col[j + 2], c3 = col[j + 3];
        ushort4 h0 = *(const ushort4*)(Hb + (size_t)c0 * 256);
        ushort4 h1 = *(const ushort4*)(Hb + (size_t)c1 * 256);
        ushort4 h2 = *(const ushort4*)(Hb + (size_t)c2 * 256);
        ushort4 h3 = *(const ushort4*)(Hb + (size_t)c3 * 256);
        a0 += b2f(h0.x) + b2f(h1.x) + b2f(h2.x) + b2f(h3.x);
        a1 += b2f(h0.y) + b2f(h1.y) + b2f(h2.y) + b2f(h3.y);
        a2 += b2f(h0.z) + b2f(h1.z) + b2f(h2.z) + b2f(h3.z);
        a3 += b2f(h0.w) + b2f(h1.w) + b2f(h2.w) + b2f(h3.w);
    }
    for (; j < e; j++) {
        int c = col[j];
        ushort4 h = *(const ushort4*)(Hb + (size_t)c * 256);
        a0 += b2f(h.x); a1 += b2f(h.y); a2 += b2f(h.z); a3 += b2f(h.w);
    }
    u16* xp = Xn + (size_t)n * 256 + 4 * lane;
    ushort4 xv = *(const ushort4*)xp;
    float v0 = fmaxf(b2f(xv.x) + a0 * inv, 0.0f);
    float v1 = fmaxf(b2f(xv.y) + a1 * inv, 0.0f);
    float v2 = fmaxf(b2f(xv.z) + a2 * inv, 0.0f);
    float v3 = fmaxf(b2f(xv.w) + a3 * inv, 0.0f);
    ushort4 o;
    o.x = f2b(v0); o.y = f2b(v1); o.z = f2b(v2); o.w = f2b(v3);
    *(ushort4*)xp = o;
    if (DOT) {
        float4 wv4 = *(const float4*)(w + 4 * lane);
        float d = v0 * wv4.x + v1 * wv4.y + v2 * wv4.z + v3 * wv4.w;
        #pragma unroll
        for (int off = 32; off > 0; off >>= 1) d += __shfl_down(d, off);
        if (lane == 0) dotbuf[n] = d;
    }
}

// ---------------------------------------------------------------- pool reduce + head
__global__ void out_init_k(float* __restrict__ out, const float* __restrict__ headb) {
    int i = threadIdx.x;
    if (i < G_GRAPH * S_SAMP) out[i] = headb[0];
}

__global__ __launch_bounds__(256) void reduce_k(const float* __restrict__ dotbuf,
                                                const int* __restrict__ batch,
                                                float* __restrict__ out, int s) {
    __shared__ float part[G_GRAPH];
    if (threadIdx.x < G_GRAPH) part[threadIdx.x] = 0.0f;
    __syncthreads();
    for (int i = blockIdx.x * 256 + threadIdx.x; i < N_NODES; i += gridDim.x * 256)
        atomicAdd(&part[batch[i]], dotbuf[i]);
    __syncthreads();
    if (threadIdx.x < G_GRAPH)
        atomicAdd(&out[threadIdx.x * S_SAMP + s], part[threadIdx.x]);
}

// ---------------------------------------------------------------- launch
extern "C" void kernel_launch(void* const* d_in, const int* in_sizes, int n_in,
                              void* d_out, int out_size, void* d_ws, size_t ws_size,
                              hipStream_t stream) {
    const float* x_feat      = (const float*)d_in[0];
    const float* dim_feat    = (const float*)d_in[1];
    const float* layout_feat = (const float*)d_in[2];
    const float* tile_feat   = (const float*)d_in[3];
    const float* opemb       = (const float*)d_in[4];
    const float* preW        = (const float*)d_in[5];
    const float* preb        = (const float*)d_in[6];
    const float* convWl      = (const float*)d_in[7];
    const float* convWr      = (const float*)d_in[8];
    const float* convb       = (const float*)d_in[9];
    const float* revWl       = (const float*)d_in[10];
    const float* revWr       = (const float*)d_in[11];
    const float* revb        = (const float*)d_in[12];
    const float* headW       = (const float*)d_in[13];
    const float* headb       = (const float*)d_in[14];
    const int*   node_opcode = (const int*)d_in[15];
    const int*   batch       = (const int*)d_in[16];
    const int*   edge_index  = (const int*)d_in[17];
    float* out = (float*)d_out;

    char* ws = (char*)d_ws;
    size_t off = 0;
    auto alloc = [&](size_t nbytes) {
        char* p = ws + off;
        off += (nbytes + 255) & ~(size_t)255;
        return p;
    };
    u16* XA    = (u16*)alloc((size_t)NPAD * 256 * 2);      // padded rows for async staging
    u16* XB    = (u16*)alloc((size_t)NPAD * 256 * 2);
    u16* XinH  = (u16*)alloc((size_t)N_NODES * KPRE * 2);  // Xin, then reused as H
    u16* Wt    = (u16*)alloc((size_t)NLAYER * 512 * 256 * 2);
    u16* preWt = (u16*)alloc((size_t)256 * KPRE * 2);
    float* bcat = (float*)alloc(NLAYER * 512 * 4);
    float* dotbuf = (float*)alloc((size_t)N_NODES * 4);
    int* degF  = (int*)alloc(N_NODES * 4);
    int* degR  = (int*)alloc(N_NODES * 4);
    int* rpF   = (int*)alloc((N_NODES + 1) * 4);
    int* rpR   = (int*)alloc((N_NODES + 1) * 4);
    int* curF  = (int*)alloc(N_NODES * 4);
    int* curR  = (int*)alloc(N_NODES * 4);
    int* colF  = (int*)alloc(E_EDGES * 4);
    int* colR  = (int*)alloc(E_EDGES * 4);
    int* bsum  = (int*)alloc(2 * NB1 * 4);
    float* invF = (float*)alloc(N_NODES * 4);
    float* invR = (float*)alloc(N_NODES * 4);

    hipMemsetAsync(degF, 0, N_NODES * 4, stream);
    hipMemsetAsync(degR, 0, N_NODES * 4, stream);

    pack_w_k<<<(NLAYER * 512 * 256 + 255) / 256, 256, 0, stream>>>(
        convWl, revWl, convWr, revWr, convb, revb, Wt, bcat);
    pack_pre_k<<<(256 * KPRE + 255) / 256, 256, 0, stream>>>(preW, preWt);
    deg_k<<<(E_EDGES + 255) / 256, 256, 0, stream>>>(edge_index, degF, degR);
    scan1_k<<<dim3(NB1, 2), 1024, 0, stream>>>(degF, degR, rpF, rpR, bsum);
    scan2_k<<<1, 256, 0, stream>>>(bsum, rpF, rpR);
    scan3_k<<<dim3(NB1, 2), 1024, 0, stream>>>(bsum, rpF, rpR);
    inv_cursor_k<<<(N_NODES + 255) / 256, 256, 0, stream>>>(
        degF, degR, rpF, rpR, invF, invR, curF, curR);
    fill_k<<<(E_EDGES + 255) / 256, 256, 0, stream>>>(edge_index, curF, curR, colF, colR);

    out_init_k<<<1, 64, 0, stream>>>(out, headb);

    for (int s = 0; s < S_SAMP; s++) {
        build_xin_k<<<N_NODES, 256, 0, stream>>>(
            x_feat, dim_feat, layout_feat, tile_feat, opemb, node_opcode, batch, s, XinH);
        // X0 = relu(Xin @ preW + preb)  (stored POST-relu)
        mm_sw_k<true, 96, 4><<<NGRP * 8 * 4, 256, 0, stream>>>(
            XinH, KPRE, N_NODES, preWt, preb, XA);

        u16* ins[NLAYER]  = {XA, XB, XA, XB};
        u16* outs[NLAYER] = {XB, XA, XB, XA};
        for (int l = 0; l < NLAYER; l++) {
            // fused: [P | H] = x~ @ [Wr_cat | Wl_cat] + [b_cat | 0]
            mmL_k<<<NGRP * 8 * 8, 256, 0, stream>>>(
                ins[l], Wt + (size_t)l * 512 * 256, bcat + (size_t)l * 512,
                outs[l], XinH);
            // X_next~ = relu(P + inv-scaled gathered messages)  [+ pooled dot]
            if (l < 2) {
                agg_k<false><<<(N_NODES * 64 + 255) / 256, 256, 0, stream>>>(
                    rpF, colF, rpR, colR, invF, invR, XinH, outs[l], nullptr, nullptr);
            } else {
                agg_k<true><<<(N_NODES * 64 + 255) / 256, 256, 0, stream>>>(
                    rpF, colF, rpR, colR, invF, invR, XinH, outs[l],
                    headW + (l == 2 ? 0 : 256), dotbuf);
                reduce_k<<<128, 256, 0, stream>>>(dotbuf, batch, out, s);
            }
        }
    }
}

// Round 8
// 1504.140 us; speedup vs baseline: 1.7936x; 1.2044x over previous
//
#include <hip/hip_runtime.h>
#include <hip/hip_bf16.h>

#define N_NODES 100000
#define S_SAMP 2
#define G_GRAPH 8
#define E_EDGES 400000
#define NLAYER 4
#define IN_CH 265
#define KPRE 384                        // 265 padded to 3*128 (zero-filled)
#define NRT64 ((N_NODES + 63) / 64)     // 1563 row tiles
#define NPAD (NRT64 * 64)               // 100032 padded rows for X buffers
#define NGRP ((NRT64 + 7) / 8)          // 196 row-tile groups (8 -> 8 XCDs)
#define NB1 ((N_NODES + 1023) / 1024)   // 98 scan blocks

typedef unsigned short u16;
typedef unsigned int u32;
typedef short bf16x8 __attribute__((ext_vector_type(8)));
typedef float f32x4 __attribute__((ext_vector_type(4)));

__device__ __forceinline__ float b2f(u16 u) {
    union { u32 i; float f; } x; x.i = ((u32)u) << 16; return x.f;
}
__device__ __forceinline__ u16 f2b(float f) {
    __hip_bfloat16 h = __float2bfloat16(f);
    return *reinterpret_cast<u16*>(&h);
}

// async global->LDS, 16B per lane; lds dest = wave-uniform base + lane*16
__device__ __forceinline__ void gl_lds16(const u16* g, u16* l) {
    __builtin_amdgcn_global_load_lds(
        (const __attribute__((address_space(1))) void*)g,
        (__attribute__((address_space(3))) void*)l, 16, 0, 0);
}

// ---------------------------------------------------------------- features (per s)
__global__ void build_xin_k(const float* __restrict__ xf,
                            const float* __restrict__ dimf,
                            const float* __restrict__ layf,
                            const float* __restrict__ tilef,
                            const float* __restrict__ opemb,
                            const int* __restrict__ opcode,
                            const int* __restrict__ batch,
                            int s, u16* __restrict__ xin) {
    int n = blockIdx.x;
    int opc = opcode[n];
    int g = batch[n];
    u16* row = xin + (size_t)n * KPRE;
    for (int c = threadIdx.x; c < KPRE; c += blockDim.x) {
        float v = 0.0f;
        if (c < 53)       v = xf[(size_t)n * 53 + c];
        else if (c < 85)  v = opemb[opc * 32 + (c - 53)];
        else if (c < 223) v = dimf[(size_t)n * 138 + (c - 85)];
        else if (c < 247) v = layf[((size_t)n * S_SAMP + s) * 24 + (c - 223)];
        else if (c < 265) v = tilef[((size_t)g * S_SAMP + s) * 18 + (c - 247)];
        row[c] = f2b(v);
    }
}

// ---------------------------------------------------------------- weight packing (transposed)
// Wt: [L][512][256] bf16.  n<256 -> Wr_cat (X_next), n>=256 -> Wl_cat (H).
// Within each 256: col<128 = conv, col>=128 = rev.   bcat: [L][512] (upper 256 zero)
__global__ void pack_w_k(const float* __restrict__ cWl, const float* __restrict__ rWl,
                         const float* __restrict__ cWr, const float* __restrict__ rWr,
                         const float* __restrict__ cb,  const float* __restrict__ rb,
                         u16* __restrict__ Wt, float* __restrict__ bcat) {
    int idx = blockIdx.x * blockDim.x + threadIdx.x;   // L*512*256
    if (idx < NLAYER * 512 * 256) {
        int l = idx >> 17;
        int r = idx & 131071;
        int j = r >> 8;            // output col 0..511
        int k = r & 255;
        int jj = j & 255;
        int half = j >> 8;         // 0 = Wr, 1 = Wl
        int sub = jj >> 7;         // 0 = conv, 1 = rev
        int col = jj & 127;
        const float* src = half ? (sub ? rWl : cWl) : (sub ? rWr : cWr);
        Wt[idx] = f2b(src[((size_t)l * 256 + k) * 128 + col]);
    }
    if (idx < NLAYER * 512) {
        int l = idx >> 9;
        int j = idx & 511;
        float v = 0.0f;
        if (j < 256) v = (j < 128) ? cb[l * 128 + j] : rb[l * 128 + (j - 128)];
        bcat[idx] = v;
    }
}

// preWt: [256][KPRE] bf16 (transposed, zero-padded K)
__global__ void pack_pre_k(const float* __restrict__ preW, u16* __restrict__ preWt) {
    int idx = blockIdx.x * blockDim.x + threadIdx.x;
    if (idx >= 256 * KPRE) return;
    int j = idx / KPRE;
    int k = idx - j * KPRE;
    preWt[idx] = (k < IN_CH) ? f2b(preW[(size_t)k * 256 + j]) : (u16)0;
}

// ---------------------------------------------------------------- degrees + CSR
__global__ void deg_k(const int* __restrict__ ei, int* __restrict__ degF,
                      int* __restrict__ degR) {
    int e = blockIdx.x * blockDim.x + threadIdx.x;
    if (e < E_EDGES) {
        atomicAdd(&degF[ei[E_EDGES + e]], 1);
        atomicAdd(&degR[ei[e]], 1);
    }
}

__global__ __launch_bounds__(1024) void scan1_k(const int* __restrict__ degF,
                                                const int* __restrict__ degR,
                                                int* __restrict__ rpF,
                                                int* __restrict__ rpR,
                                                int* __restrict__ bsum) {
    const int* deg = blockIdx.y ? degR : degF;
    int* rp = blockIdx.y ? rpR : rpF;
    __shared__ int buf[1024];
    int i = blockIdx.x * 1024 + threadIdx.x;
    int v = (i < N_NODES) ? deg[i] : 0;
    buf[threadIdx.x] = v;
    __syncthreads();
    for (int off = 1; off < 1024; off <<= 1) {
        int t = (threadIdx.x >= off) ? buf[threadIdx.x - off] : 0;
        __syncthreads();
        buf[threadIdx.x] += t;
        __syncthreads();
    }
    if (i < N_NODES) rp[i] = buf[threadIdx.x] - v;
    if (threadIdx.x == 1023) bsum[blockIdx.y * NB1 + blockIdx.x] = buf[1023];
}

__global__ __launch_bounds__(256) void scan2_k(int* __restrict__ bsum,
                                               int* __restrict__ rpF,
                                               int* __restrict__ rpR) {
    __shared__ int buf[2][128];
    int half = threadIdx.x >> 7;
    int t = threadIdx.x & 127;
    int v = (t < NB1) ? bsum[half * NB1 + t] : 0;
    buf[half][t] = v;
    __syncthreads();
    for (int off = 1; off < 128; off <<= 1) {
        int x = (t >= off) ? buf[half][t - off] : 0;
        __syncthreads();
        buf[half][t] += x;
        __syncthreads();
    }
    if (t < NB1) bsum[half * NB1 + t] = buf[half][t] - v;
    if (t == NB1) (half ? rpR : rpF)[N_NODES] = buf[half][NB1 - 1];
}

__global__ void scan3_k(const int* __restrict__ bsum, int* __restrict__ rpF,
                        int* __restrict__ rpR) {
    int* rp = blockIdx.y ? rpR : rpF;
    int i = blockIdx.x * 1024 + threadIdx.x;
    if (i < N_NODES) rp[i] += bsum[blockIdx.y * NB1 + blockIdx.x];
}

__global__ void inv_cursor_k(const int* __restrict__ degF, const int* __restrict__ degR,
                             const int* __restrict__ rpF, const int* __restrict__ rpR,
                             float* __restrict__ invF, float* __restrict__ invR,
                             int* __restrict__ curF, int* __restrict__ curR) {
    int i = blockIdx.x * blockDim.x + threadIdx.x;
    if (i < N_NODES) {
        invF[i] = 1.0f / fmaxf((float)degF[i], 1.0f);
        invR[i] = 1.0f / fmaxf((float)degR[i], 1.0f);
        curF[i] = rpF[i];
        curR[i] = rpR[i];
    }
}

__global__ void fill_k(const int* __restrict__ ei, int* __restrict__ curF,
                       int* __restrict__ curR, int* __restrict__ colF,
                       int* __restrict__ colR) {
    int e = blockIdx.x * blockDim.x + threadIdx.x;
    if (e < E_EDGES) {
        int s = ei[e], t = ei[E_EDGES + e];
        colF[atomicAdd(&curF[t], 1)] = s;
        colR[atomicAdd(&curR[s], 1)] = t;
    }
}

// ---------------------------------------------------------------- MFMA GEMM (unified, DMA-staged, hi-occ)
// C[M=Npad rows, N=COLT*64 cols] = A @ Bt^T + bias.  64x64 tile, 256 thr, 4 waves.
// K = NCHUNK*128, staged in 128-wide chunks via global_load_lds (16B/lane).
// XOR slot swizzle (slot = ch ^ (row&15)): staging contiguous per DMA instr,
// b128 fragment reads spread uniformly over all 8 bank groups (conflict-free).
// LDS 32 KB -> 5 blocks/CU.  XCD swizzle: bid = g*(8*COLT) + c*8 + x.
// Global col<256 -> C0 (+bias), else C1 (H).
template <bool RELU_OUT, int NCHUNK, int COLT>
__global__ __launch_bounds__(256) void mmA_k(const u16* __restrict__ A,
                                             const u16* __restrict__ Bt,
                                             const float* __restrict__ bias,
                                             u16* __restrict__ C0,
                                             u16* __restrict__ C1) {
    __shared__ u16 As[64 * 128];
    __shared__ u16 Bs[64 * 128];
    constexpr int K = NCHUNK * 128;

    int bid = blockIdx.x;
    int x = bid & 7;
    int q = bid >> 3;
    int c = q % COLT;
    int g = q / COLT;
    int rowTile = g * 8 + x;
    if (rowTile >= NRT64) return;
    int rowBase = rowTile * 64;
    int colBase = c * 64;

    int tid = threadIdx.x;
    int wv = tid >> 6;
    int lane = tid & 63;
    int quad = lane >> 4;
    int l16 = lane & 15;

    // staging decomposition: one DMA instr = 1 KB = 4 rows x 256 B.
    // lane l -> row += l>>4, slot = l&15; fetch global chunk ch = slot ^ (row&15)
    int rsub = lane >> 4;
    int sl = lane & 15;

    f32x4 acc[4] = {};

    for (int ci = 0; ci < NCHUNK; ci++) {
        int k0 = ci * 128;
        #pragma unroll
        for (int i = 0; i < 4; i++) {
            int r = wv * 16 + 4 * i + rsub;          // tile row 0..63
            int ch = sl ^ (r & 15);
            gl_lds16(A + (size_t)(rowBase + r) * K + k0 + ch * 8,
                     As + (wv * 16 + 4 * i) * 128);
            gl_lds16(Bt + (size_t)(colBase + r) * K + k0 + ch * 8,
                     Bs + (wv * 16 + 4 * i) * 128);
        }
        __syncthreads();                              // vmcnt drain + barrier
        int ra = wv * 16 + l16;
        #pragma unroll
        for (int ks = 0; ks < 4; ks++) {
            int ca = ks * 4 + quad;
            bf16x8 af = *(const bf16x8*)(As + ra * 128 + (ca ^ (ra & 15)) * 8);
            #pragma unroll
            for (int cf = 0; cf < 4; cf++) {
                int rb = cf * 16 + l16;
                bf16x8 bf = *(const bf16x8*)(Bs + rb * 128 + (ca ^ (rb & 15)) * 8);
                acc[cf] = __builtin_amdgcn_mfma_f32_16x16x32_bf16(af, bf, acc[cf], 0, 0, 0);
            }
        }
        if (ci + 1 < NCHUNK) __syncthreads();         // protect LDS reuse
    }

    // epilogue: C/D layout col=lane&15, row=quad*4+reg
    u16* dst = (colBase < 256) ? C0 : C1;
    int cb = colBase & 255;
    #pragma unroll
    for (int cf = 0; cf < 4; cf++) {
        int col = cb + cf * 16 + l16;
        float bv = bias[colBase + cf * 16 + l16];
        #pragma unroll
        for (int r = 0; r < 4; r++) {
            int row = rowBase + wv * 16 + quad * 4 + r;
            if (row < N_NODES) {
                float v = acc[cf][r] + bv;
                if (RELU_OUT) v = fmaxf(v, 0.0f);
                dst[(size_t)row * 256 + col] = f2b(v);
            }
        }
    }
}

// ---------------------------------------------------------------- aggregation (CSR gather)
// One wave per node. Lanes 0-31: fwd half (H[.,0:128]); lanes 32-63: rev half.
// X := relu(X + inv * gathered). If DOT: also dotbuf[n] = X_new . w (w = headW slice).
template <bool DOT>
__global__ __launch_bounds__(256) void agg_k(const int* __restrict__ rpF,
                                             const int* __restrict__ colF,
                                             const int* __restrict__ rpR,
                                             const int* __restrict__ colR,
                                             const float* __restrict__ invF,
                                             const float* __restrict__ invR,
                                             const u16* __restrict__ H,
                                             u16* __restrict__ Xn,
                                             const float* __restrict__ w,
                                             float* __restrict__ dotbuf) {
    int n = (blockIdx.x * blockDim.x + threadIdx.x) >> 6;
    if (n >= N_NODES) return;
    int lane = threadIdx.x & 63;
    int half = lane >> 5;
    int l32 = lane & 31;
    const int* rp  = half ? rpR : rpF;
    const int* col = half ? colR : colF;
    float inv = half ? invR[n] : invF[n];
    const u16* Hb = H + half * 128 + 4 * l32;

    float a0 = 0, a1 = 0, a2 = 0, a3 = 0;
    int b = rp[n], e = rp[n + 1];
    int j = b;
    for (; j + 7 < e; j += 8) {
        int c0 = col[j],     c1 = col[j + 1], c2 = col[j + 2], c3 = col[j + 3];
        int c4 = col[j + 4], c5 = col[j + 5], c6 = col[j + 6], c7 = col[j + 7];
        ushort4 h0 = *(const ushort4*)(Hb + (size_t)c0 * 256);
        ushort4 h1 = *(const ushort4*)(Hb + (size_t)c1 * 256);
        ushort4 h2 = *(const ushort4*)(Hb + (size_t)c2 * 256);
        ushort4 h3 = *(const ushort4*)(Hb + (size_t)c3 * 256);
        ushort4 h4 = *(const ushort4*)(Hb + (size_t)c4 * 256);
        ushort4 h5 = *(const ushort4*)(Hb + (size_t)c5 * 256);
        ushort4 h6 = *(const ushort4*)(Hb + (size_t)c6 * 256);
        ushort4 h7 = *(const ushort4*)(Hb + (size_t)c7 * 256);
        a0 += b2f(h0.x) + b2f(h1.x) + b2f(h2.x) + b2f(h3.x)
            + b2f(h4.x) + b2f(h5.x) + b2f(h6.x) + b2f(h7.x);
        a1 += b2f(h0.y) + b2f(h1.y) + b2f(h2.y) + b2f(h3.y)
            + b2f(h4.y) + b2f(h5.y) + b2f(h6.y) + b2f(h7.y);
        a2 += b2f(h0.z) + b2f(h1.z) + b2f(h2.z) + b2f(h3.z)
            + b2f(h4.z) + b2f(h5.z) + b2f(h6.z) + b2f(h7.z);
        a3 += b2f(h0.w) + b2f(h1.w) + b2f(h2.w) + b2f(h3.w)
            + b2f(h4.w) + b2f(h5.w) + b2f(h6.w) + b2f(h7.w);
    }
    for (; j + 3 < e; j += 4) {
        int c0 = col[j], c1 = col[j + 1], c2 = col[j + 2], c3 = col[j + 3];
        ushort4 h0 = *(const ushort4*)(Hb + (size_t)c0 * 256);
        ushort4 h1 = *(const ushort4*)(Hb + (size_t)c1 * 256);
        ushort4 h2 = *(const ushort4*)(Hb + (size_t)c2 * 256);
        ushort4 h3 = *(const ushort4*)(Hb + (size_t)c3 * 256);
        a0 += b2f(h0.x) + b2f(h1.x) + b2f(h2.x) + b2f(h3.x);
        a1 += b2f(h0.y) + b2f(h1.y) + b2f(h2.y) + b2f(h3.y);
        a2 += b2f(h0.z) + b2f(h1.z) + b2f(h2.z) + b2f(h3.z);
        a3 += b2f(h0.w) + b2f(h1.w) + b2f(h2.w) + b2f(h3.w);
    }
    for (; j < e; j++) {
        int c = col[j];
        ushort4 h = *(const ushort4*)(Hb + (size_t)c * 256);
        a0 += b2f(h.x); a1 += b2f(h.y); a2 += b2f(h.z); a3 += b2f(h.w);
    }
    u16* xp = Xn + (size_t)n * 256 + 4 * lane;
    ushort4 xv = *(const ushort4*)xp;
    float v0 = fmaxf(b2f(xv.x) + a0 * inv, 0.0f);
    float v1 = fmaxf(b2f(xv.y) + a1 * inv, 0.0f);
    float v2 = fmaxf(b2f(xv.z) + a2 * inv, 0.0f);
    float v3 = fmaxf(b2f(xv.w) + a3 * inv, 0.0f);
    ushort4 o;
    o.x = f2b(v0); o.y = f2b(v1); o.z = f2b(v2); o.w = f2b(v3);
    *(ushort4*)xp = o;
    if (DOT) {
        float4 wv4 = *(const float4*)(w + 4 * lane);
        float d = v0 * wv4.x + v1 * wv4.y + v2 * wv4.z + v3 * wv4.w;
        #pragma unroll
        for (int off = 32; off > 0; off >>= 1) d += __shfl_down(d, off);
        if (lane == 0) dotbuf[n] = d;
    }
}

// ---------------------------------------------------------------- pool reduce + head
__global__ void out_init_k(float* __restrict__ out, const float* __restrict__ headb) {
    int i = threadIdx.x;
    if (i < G_GRAPH * S_SAMP) out[i] = headb[0];
}

__global__ __launch_bounds__(256) void reduce_k(const float* __restrict__ dotbuf,
                                                const int* __restrict__ batch,
                                                float* __restrict__ out, int s) {
    __shared__ float part[G_GRAPH];
    if (threadIdx.x < G_GRAPH) part[threadIdx.x] = 0.0f;
    __syncthreads();
    for (int i = blockIdx.x * 256 + threadIdx.x; i < N_NODES; i += gridDim.x * 256)
        atomicAdd(&part[batch[i]], dotbuf[i]);
    __syncthreads();
    if (threadIdx.x < G_GRAPH)
        atomicAdd(&out[threadIdx.x * S_SAMP + s], part[threadIdx.x]);
}

// ---------------------------------------------------------------- launch
extern "C" void kernel_launch(void* const* d_in, const int* in_sizes, int n_in,
                              void* d_out, int out_size, void* d_ws, size_t ws_size,
                              hipStream_t stream) {
    const float* x_feat      = (const float*)d_in[0];
    const float* dim_feat    = (const float*)d_in[1];
    const float* layout_feat = (const float*)d_in[2];
    const float* tile_feat   = (const float*)d_in[3];
    const float* opemb       = (const float*)d_in[4];
    const float* preW        = (const float*)d_in[5];
    const float* preb        = (const float*)d_in[6];
    const float* convWl      = (const float*)d_in[7];
    const float* convWr      = (const float*)d_in[8];
    const float* convb       = (const float*)d_in[9];
    const float* revWl       = (const float*)d_in[10];
    const float* revWr       = (const float*)d_in[11];
    const float* revb        = (const float*)d_in[12];
    const float* headW       = (const float*)d_in[13];
    const float* headb       = (const float*)d_in[14];
    const int*   node_opcode = (const int*)d_in[15];
    const int*   batch       = (const int*)d_in[16];
    const int*   edge_index  = (const int*)d_in[17];
    float* out = (float*)d_out;

    char* ws = (char*)d_ws;
    size_t off = 0;
    auto alloc = [&](size_t nbytes) {
        char* p = ws + off;
        off += (nbytes + 255) & ~(size_t)255;
        return p;
    };
    u16* XA    = (u16*)alloc((size_t)NPAD * 256 * 2);      // padded rows for DMA staging
    u16* XB    = (u16*)alloc((size_t)NPAD * 256 * 2);
    u16* XinH  = (u16*)alloc((size_t)NPAD * KPRE * 2);     // Xin (K=384), then reused as H
    u16* Wt    = (u16*)alloc((size_t)NLAYER * 512 * 256 * 2);
    u16* preWt = (u16*)alloc((size_t)256 * KPRE * 2);
    float* bcat = (float*)alloc(NLAYER * 512 * 4);
    float* dotbuf = (float*)alloc((size_t)N_NODES * 4);
    int* degF  = (int*)alloc(N_NODES * 4);
    int* degR  = (int*)alloc(N_NODES * 4);
    int* rpF   = (int*)alloc((N_NODES + 1) * 4);
    int* rpR   = (int*)alloc((N_NODES + 1) * 4);
    int* curF  = (int*)alloc(N_NODES * 4);
    int* curR  = (int*)alloc(N_NODES * 4);
    int* colF  = (int*)alloc(E_EDGES * 4);
    int* colR  = (int*)alloc(E_EDGES * 4);
    int* bsum  = (int*)alloc(2 * NB1 * 4);
    float* invF = (float*)alloc(N_NODES * 4);
    float* invR = (float*)alloc(N_NODES * 4);

    hipMemsetAsync(degF, 0, N_NODES * 4, stream);
    hipMemsetAsync(degR, 0, N_NODES * 4, stream);

    pack_w_k<<<(NLAYER * 512 * 256 + 255) / 256, 256, 0, stream>>>(
        convWl, revWl, convWr, revWr, convb, revb, Wt, bcat);
    pack_pre_k<<<(256 * KPRE + 255) / 256, 256, 0, stream>>>(preW, preWt);
    deg_k<<<(E_EDGES + 255) / 256, 256, 0, stream>>>(edge_index, degF, degR);
    scan1_k<<<dim3(NB1, 2), 1024, 0, stream>>>(degF, degR, rpF, rpR, bsum);
    scan2_k<<<1, 256, 0, stream>>>(bsum, rpF, rpR);
    scan3_k<<<dim3(NB1, 2), 1024, 0, stream>>>(bsum, rpF, rpR);
    inv_cursor_k<<<(N_NODES + 255) / 256, 256, 0, stream>>>(
        degF, degR, rpF, rpR, invF, invR, curF, curR);
    fill_k<<<(E_EDGES + 255) / 256, 256, 0, stream>>>(edge_index, curF, curR, colF, colR);

    out_init_k<<<1, 64, 0, stream>>>(out, headb);

    for (int s = 0; s < S_SAMP; s++) {
        build_xin_k<<<N_NODES, 256, 0, stream>>>(
            x_feat, dim_feat, layout_feat, tile_feat, opemb, node_opcode, batch, s, XinH);
        // X0 = relu(Xin @ preW + preb)  (stored POST-relu); K=384 = 3 chunks
        mmA_k<true, 3, 4><<<NGRP * 8 * 4, 256, 0, stream>>>(
            XinH, preWt, preb, XA, XA);

        u16* ins[NLAYER]  = {XA, XB, XA, XB};
        u16* outs[NLAYER] = {XB, XA, XB, XA};
        for (int l = 0; l < NLAYER; l++) {
            // fused: [P | H] = x~ @ [Wr_cat | Wl_cat] + [b_cat | 0]; K=256 = 2 chunks
            mmA_k<false, 2, 8><<<NGRP * 8 * 8, 256, 0, stream>>>(
                ins[l], Wt + (size_t)l * 512 * 256, bcat + (size_t)l * 512,
                outs[l], XinH);
            // X_next~ = relu(P + inv-scaled gathered messages)  [+ pooled dot]
            if (l < 2) {
                agg_k<false><<<(N_NODES * 64 + 255) / 256, 256, 0, stream>>>(
                    rpF, colF, rpR, colR, invF, invR, XinH, outs[l], nullptr, nullptr);
            } else {
                agg_k<true><<<(N_NODES * 64 + 255) / 256, 256, 0, stream>>>(
                    rpF, colF, rpR, colR, invF, invR, XinH, outs[l],
                    headW + (l == 2 ? 0 : 256), dotbuf);
                reduce_k<<<128, 256, 0, stream>>>(dotbuf, batch, out, s);
            }
        }
    }
}

// Round 9
// 1457.634 us; speedup vs baseline: 1.8508x; 1.0319x over previous
//
#include <hip/hip_runtime.h>
#include <hip/hip_bf16.h>

#define N_NODES 100000
#define S_SAMP 2
#define G_GRAPH 8
#define E_EDGES 400000
#define NLAYER 4
#define IN_CH 265
#define KPRE 384                        // K padded to 3*128 chunks
#define NRT64 ((N_NODES + 63) / 64)     // 1563 row tiles (per-s)
#define NPAD (NRT64 * 64)               // 100032
#define NB1 ((N_NODES + 1023) / 1024)   // 98 scan blocks
#define M2 (S_SAMP * N_NODES)           // 200000 = 3125 * 64 exactly
#define MT2 (M2 / 64)                   // 3125

typedef unsigned short u16;
typedef unsigned int u32;
typedef short bf16x8 __attribute__((ext_vector_type(8)));
typedef float f32x4 __attribute__((ext_vector_type(4)));

__device__ __forceinline__ float b2f(u16 u) {
    union { u32 i; float f; } x; x.i = ((u32)u) << 16; return x.f;
}
__device__ __forceinline__ u16 f2b(float f) {
    __hip_bfloat16 h = __float2bfloat16(f);
    return *reinterpret_cast<u16*>(&h);
}

// async global->LDS, 16B per lane; lds dest = wave-uniform base + lane*16
__device__ __forceinline__ void gl_lds16(const u16* g, u16* l) {
    __builtin_amdgcn_global_load_lds(
        (const __attribute__((address_space(1))) void*)g,
        (__attribute__((address_space(3))) void*)l, 16, 0, 0);
}

// ---------------------------------------------------------------- features
// merged build: A2[n][384] = [base(223) | lay_s0,tile_s0(42) | lay_s1,tile_s1(42) | pad]
// one thread per (node, 4-chan chunk); ushort4 stores. chunks 0..76 (c<308).
__global__ __launch_bounds__(256) void build_m_k(const float* __restrict__ xf,
                                                 const float* __restrict__ dimf,
                                                 const float* __restrict__ layf,
                                                 const float* __restrict__ tilef,
                                                 const float* __restrict__ opemb,
                                                 const int* __restrict__ opcode,
                                                 const int* __restrict__ batch,
                                                 u16* __restrict__ A2) {
    int item = blockIdx.x * blockDim.x + threadIdx.x;
    int n = item / 77;
    if (n >= N_NODES) return;
    int base = (item - n * 77) * 4;
    int opc = opcode[n];
    int g = batch[n];
    ushort4 o;
    u16* op = &o.x;
    #pragma unroll
    for (int u = 0; u < 4; u++) {
        int c = base + u;
        float v = 0.0f;
        if (c < 53)       v = xf[(size_t)n * 53 + c];
        else if (c < 85)  v = opemb[opc * 32 + (c - 53)];
        else if (c < 223) v = dimf[(size_t)n * 138 + (c - 85)];
        else if (c < 247) v = layf[((size_t)n * 2 + 0) * 24 + (c - 223)];
        else if (c < 265) v = tilef[((size_t)g * 2 + 0) * 18 + (c - 247)];
        else if (c < 289) v = layf[((size_t)n * 2 + 1) * 24 + (c - 265)];
        else if (c < 307) v = tilef[((size_t)g * 2 + 1) * 18 + (c - 289)];
        op[u] = f2b(v);
    }
    *(ushort4*)(A2 + (size_t)n * KPRE + base) = o;
}

// per-s build (fallback): xin[n][384], chunks 0..66 (c<268)
__global__ __launch_bounds__(256) void build_s_k(const float* __restrict__ xf,
                                                 const float* __restrict__ dimf,
                                                 const float* __restrict__ layf,
                                                 const float* __restrict__ tilef,
                                                 const float* __restrict__ opemb,
                                                 const int* __restrict__ opcode,
                                                 const int* __restrict__ batch,
                                                 int s, u16* __restrict__ xin) {
    int item = blockIdx.x * blockDim.x + threadIdx.x;
    int n = item / 67;
    if (n >= N_NODES) return;
    int base = (item - n * 67) * 4;
    int opc = opcode[n];
    int g = batch[n];
    ushort4 o;
    u16* op = &o.x;
    #pragma unroll
    for (int u = 0; u < 4; u++) {
        int c = base + u;
        float v = 0.0f;
        if (c < 53)       v = xf[(size_t)n * 53 + c];
        else if (c < 85)  v = opemb[opc * 32 + (c - 53)];
        else if (c < 223) v = dimf[(size_t)n * 138 + (c - 85)];
        else if (c < 247) v = layf[((size_t)n * 2 + s) * 24 + (c - 223)];
        else if (c < 265) v = tilef[((size_t)g * 2 + s) * 18 + (c - 247)];
        op[u] = f2b(v);
    }
    *(ushort4*)(xin + (size_t)n * KPRE + base) = o;
}

// ---------------------------------------------------------------- weight packing
// Wt: [L][512][256] bf16 transposed.  col<256 -> Wr_cat (P), col>=256 -> Wl_cat (H).
__global__ void pack_w_k(const float* __restrict__ cWl, const float* __restrict__ rWl,
                         const float* __restrict__ cWr, const float* __restrict__ rWr,
                         const float* __restrict__ cb,  const float* __restrict__ rb,
                         u16* __restrict__ Wt, float* __restrict__ bcat) {
    int idx = blockIdx.x * blockDim.x + threadIdx.x;
    if (idx < NLAYER * 512 * 256) {
        int l = idx >> 17;
        int r = idx & 131071;
        int j = r >> 8;
        int k = r & 255;
        int jj = j & 255;
        int half = j >> 8;
        int sub = jj >> 7;
        int col = jj & 127;
        const float* src = half ? (sub ? rWl : cWl) : (sub ? rWr : cWr);
        Wt[idx] = f2b(src[((size_t)l * 256 + k) * 128 + col]);
    }
    if (idx < NLAYER * 512) {
        int l = idx >> 9;
        int j = idx & 511;
        float v = 0.0f;
        if (j < 256) v = (j < 128) ? cb[l * 128 + j] : rb[l * 128 + (j - 128)];
        bcat[idx] = v;
    }
}

// fallback: preWt [256][384]
__global__ void pack_pre_k(const float* __restrict__ preW, u16* __restrict__ preWt) {
    int idx = blockIdx.x * blockDim.x + threadIdx.x;
    if (idx >= 256 * KPRE) return;
    int j = idx / KPRE;
    int k = idx - j * KPRE;
    preWt[idx] = (k < IN_CH) ? f2b(preW[(size_t)k * 256 + j]) : (u16)0;
}

// merged: W2t [512][384]; j<256 = s0 cols, j>=256 = s1 cols.  bias2[512].
__global__ void pack_pre2_k(const float* __restrict__ preW,
                            const float* __restrict__ preb,
                            u16* __restrict__ W2t, float* __restrict__ bias2) {
    int idx = blockIdx.x * blockDim.x + threadIdx.x;
    if (idx < 512 * KPRE) {
        int j = idx / KPRE;
        int k = idx - j * KPRE;
        float v = 0.0f;
        if (j < 256) {
            if (k < IN_CH) v = preW[(size_t)k * 256 + j];
        } else {
            int jj = j - 256;
            if (k < 223) v = preW[(size_t)k * 256 + jj];
            else if (k >= 265 && k < 307) v = preW[(size_t)(k - 42) * 256 + jj];
        }
        W2t[idx] = f2b(v);
    }
    if (idx < 512) bias2[idx] = preb[idx & 255];
}

// ---------------------------------------------------------------- degrees + CSR
__global__ void deg_k(const int* __restrict__ ei, int* __restrict__ degF,
                      int* __restrict__ degR) {
    int e = blockIdx.x * blockDim.x + threadIdx.x;
    if (e < E_EDGES) {
        atomicAdd(&degF[ei[E_EDGES + e]], 1);
        atomicAdd(&degR[ei[e]], 1);
    }
}

__global__ __launch_bounds__(1024) void scan1_k(const int* __restrict__ degF,
                                                const int* __restrict__ degR,
                                                int* __restrict__ rpF,
                                                int* __restrict__ rpR,
                                                int* __restrict__ bsum) {
    const int* deg = blockIdx.y ? degR : degF;
    int* rp = blockIdx.y ? rpR : rpF;
    __shared__ int buf[1024];
    int i = blockIdx.x * 1024 + threadIdx.x;
    int v = (i < N_NODES) ? deg[i] : 0;
    buf[threadIdx.x] = v;
    __syncthreads();
    for (int off = 1; off < 1024; off <<= 1) {
        int t = (threadIdx.x >= off) ? buf[threadIdx.x - off] : 0;
        __syncthreads();
        buf[threadIdx.x] += t;
        __syncthreads();
    }
    if (i < N_NODES) rp[i] = buf[threadIdx.x] - v;
    if (threadIdx.x == 1023) bsum[blockIdx.y * NB1 + blockIdx.x] = buf[1023];
}

__global__ __launch_bounds__(256) void scan2_k(int* __restrict__ bsum,
                                               int* __restrict__ rpF,
                                               int* __restrict__ rpR) {
    __shared__ int buf[2][128];
    int half = threadIdx.x >> 7;
    int t = threadIdx.x & 127;
    int v = (t < NB1) ? bsum[half * NB1 + t] : 0;
    buf[half][t] = v;
    __syncthreads();
    for (int off = 1; off < 128; off <<= 1) {
        int x = (t >= off) ? buf[half][t - off] : 0;
        __syncthreads();
        buf[half][t] += x;
        __syncthreads();
    }
    if (t < NB1) bsum[half * NB1 + t] = buf[half][t] - v;
    if (t == NB1) (half ? rpR : rpF)[N_NODES] = buf[half][NB1 - 1];
}

__global__ void scan3_k(const int* __restrict__ bsum, int* __restrict__ rpF,
                        int* __restrict__ rpR) {
    int* rp = blockIdx.y ? rpR : rpF;
    int i = blockIdx.x * 1024 + threadIdx.x;
    if (i < N_NODES) rp[i] += bsum[blockIdx.y * NB1 + blockIdx.x];
}

__global__ void inv_cursor_k(const int* __restrict__ degF, const int* __restrict__ degR,
                             const int* __restrict__ rpF, const int* __restrict__ rpR,
                             float* __restrict__ invF, float* __restrict__ invR,
                             int* __restrict__ curF, int* __restrict__ curR) {
    int i = blockIdx.x * blockDim.x + threadIdx.x;
    if (i < N_NODES) {
        invF[i] = 1.0f / fmaxf((float)degF[i], 1.0f);
        invR[i] = 1.0f / fmaxf((float)degR[i], 1.0f);
        curF[i] = rpF[i];
        curR[i] = rpR[i];
    }
}

__global__ void fill_k(const int* __restrict__ ei, int* __restrict__ curF,
                       int* __restrict__ curR, int* __restrict__ colF,
                       int* __restrict__ colR) {
    int e = blockIdx.x * blockDim.x + threadIdx.x;
    if (e < E_EDGES) {
        int s = ei[e], t = ei[E_EDGES + e];
        colF[atomicAdd(&curF[t], 1)] = s;
        colR[atomicAdd(&curR[s], 1)] = t;
    }
}

// ---------------------------------------------------------------- MFMA GEMM (DMA-staged, hi-occ)
// 64x64 tile, 256 thr. K = NCHUNK*128 via global_load_lds chunks, XOR slot
// swizzle. Global col<256 -> C0 (+bias), else C1. XCD swizzle on bid.
// M = valid rows (C-write guard), Mtiles = ceil rows/64 (grid may overshoot).
template <bool RELU_OUT, int NCHUNK, int COLT>
__global__ __launch_bounds__(256) void mmA_k(const u16* __restrict__ A,
                                             const u16* __restrict__ Bt,
                                             const float* __restrict__ bias,
                                             u16* __restrict__ C0,
                                             u16* __restrict__ C1,
                                             int M, int Mtiles) {
    __shared__ u16 As[64 * 128];
    __shared__ u16 Bs[64 * 128];
    constexpr int K = NCHUNK * 128;

    int bid = blockIdx.x;
    int x = bid & 7;
    int q = bid >> 3;
    int c = q % COLT;
    int g = q / COLT;
    int rowTile = g * 8 + x;
    if (rowTile >= Mtiles) return;
    int rowBase = rowTile * 64;
    int colBase = c * 64;

    int tid = threadIdx.x;
    int wv = tid >> 6;
    int lane = tid & 63;
    int quad = lane >> 4;
    int l16 = lane & 15;
    int rsub = lane >> 4;
    int sl = lane & 15;

    f32x4 acc[4] = {};

    for (int ci = 0; ci < NCHUNK; ci++) {
        int k0 = ci * 128;
        #pragma unroll
        for (int i = 0; i < 4; i++) {
            int r = wv * 16 + 4 * i + rsub;
            int ch = sl ^ (r & 15);
            gl_lds16(A + (size_t)(rowBase + r) * K + k0 + ch * 8,
                     As + (wv * 16 + 4 * i) * 128);
            gl_lds16(Bt + (size_t)(colBase + r) * K + k0 + ch * 8,
                     Bs + (wv * 16 + 4 * i) * 128);
        }
        __syncthreads();
        int ra = wv * 16 + l16;
        #pragma unroll
        for (int ks = 0; ks < 4; ks++) {
            int ca = ks * 4 + quad;
            bf16x8 af = *(const bf16x8*)(As + ra * 128 + (ca ^ (ra & 15)) * 8);
            #pragma unroll
            for (int cf = 0; cf < 4; cf++) {
                int rb = cf * 16 + l16;
                bf16x8 bf = *(const bf16x8*)(Bs + rb * 128 + (ca ^ (rb & 15)) * 8);
                acc[cf] = __builtin_amdgcn_mfma_f32_16x16x32_bf16(af, bf, acc[cf], 0, 0, 0);
            }
        }
        if (ci + 1 < NCHUNK) __syncthreads();
    }

    u16* dst = (colBase < 256) ? C0 : C1;
    int cb = colBase & 255;
    #pragma unroll
    for (int cf = 0; cf < 4; cf++) {
        int col = cb + cf * 16 + l16;
        float bv = bias[colBase + cf * 16 + l16];
        #pragma unroll
        for (int r = 0; r < 4; r++) {
            int row = rowBase + wv * 16 + quad * 4 + r;
            if (row < M) {
                float v = acc[cf][r] + bv;
                if (RELU_OUT) v = fmaxf(v, 0.0f);
                dst[(size_t)row * 256 + col] = f2b(v);
            }
        }
    }
}

// ---------------------------------------------------------------- aggregation (CSR gather)
// One wave per item i in [0, nodes). s = (i >= N), n = i - s*N. H row = s*N + col.
// Lanes 0-31: fwd half; 32-63: rev half. X := relu(X + inv*gather); opt dot.
template <bool DOT>
__global__ __launch_bounds__(256) void agg_k(const int* __restrict__ rpF,
                                             const int* __restrict__ colF,
                                             const int* __restrict__ rpR,
                                             const int* __restrict__ colR,
                                             const float* __restrict__ invF,
                                             const float* __restrict__ invR,
                                             const u16* __restrict__ H,
                                             u16* __restrict__ Xn,
                                             const float* __restrict__ w,
                                             float* __restrict__ dotbuf,
                                             int nodes) {
    int i = (blockIdx.x * blockDim.x + threadIdx.x) >> 6;
    if (i >= nodes) return;
    int s = (i >= N_NODES) ? 1 : 0;
    int n = i - s * N_NODES;
    int lane = threadIdx.x & 63;
    int half = lane >> 5;
    int l32 = lane & 31;
    const int* rp  = half ? rpR : rpF;
    const int* col = half ? colR : colF;
    float inv = half ? invR[n] : invF[n];
    const u16* Hb = H + ((size_t)s * N_NODES) * 256 + half * 128 + 4 * l32;

    float a0 = 0, a1 = 0, a2 = 0, a3 = 0;
    int b = rp[n], e = rp[n + 1];
    int j = b;
    for (; j + 7 < e; j += 8) {
        int c0 = col[j],     c1 = col[j + 1], c2 = col[j + 2], c3 = col[j + 3];
        int c4 = col[j + 4], c5 = col[j + 5], c6 = col[j + 6], c7 = col[j + 7];
        ushort4 h0 = *(const ushort4*)(Hb + (size_t)c0 * 256);
        ushort4 h1 = *(const ushort4*)(Hb + (size_t)c1 * 256);
        ushort4 h2 = *(const ushort4*)(Hb + (size_t)c2 * 256);
        ushort4 h3 = *(const ushort4*)(Hb + (size_t)c3 * 256);
        ushort4 h4 = *(const ushort4*)(Hb + (size_t)c4 * 256);
        ushort4 h5 = *(const ushort4*)(Hb + (size_t)c5 * 256);
        ushort4 h6 = *(const ushort4*)(Hb + (size_t)c6 * 256);
        ushort4 h7 = *(const ushort4*)(Hb + (size_t)c7 * 256);
        a0 += b2f(h0.x) + b2f(h1.x) + b2f(h2.x) + b2f(h3.x)
            + b2f(h4.x) + b2f(h5.x) + b2f(h6.x) + b2f(h7.x);
        a1 += b2f(h0.y) + b2f(h1.y) + b2f(h2.y) + b2f(h3.y)
            + b2f(h4.y) + b2f(h5.y) + b2f(h6.y) + b2f(h7.y);
        a2 += b2f(h0.z) + b2f(h1.z) + b2f(h2.z) + b2f(h3.z)
            + b2f(h4.z) + b2f(h5.z) + b2f(h6.z) + b2f(h7.z);
        a3 += b2f(h0.w) + b2f(h1.w) + b2f(h2.w) + b2f(h3.w)
            + b2f(h4.w) + b2f(h5.w) + b2f(h6.w) + b2f(h7.w);
    }
    for (; j + 3 < e; j += 4) {
        int c0 = col[j], c1 = col[j + 1], c2 = col[j + 2], c3 = col[j + 3];
        ushort4 h0 = *(const ushort4*)(Hb + (size_t)c0 * 256);
        ushort4 h1 = *(const ushort4*)(Hb + (size_t)c1 * 256);
        ushort4 h2 = *(const ushort4*)(Hb + (size_t)c2 * 256);
        ushort4 h3 = *(const ushort4*)(Hb + (size_t)c3 * 256);
        a0 += b2f(h0.x) + b2f(h1.x) + b2f(h2.x) + b2f(h3.x);
        a1 += b2f(h0.y) + b2f(h1.y) + b2f(h2.y) + b2f(h3.y);
        a2 += b2f(h0.z) + b2f(h1.z) + b2f(h2.z) + b2f(h3.z);
        a3 += b2f(h0.w) + b2f(h1.w) + b2f(h2.w) + b2f(h3.w);
    }
    for (; j < e; j++) {
        int c = col[j];
        ushort4 h = *(const ushort4*)(Hb + (size_t)c * 256);
        a0 += b2f(h.x); a1 += b2f(h.y); a2 += b2f(h.z); a3 += b2f(h.w);
    }
    u16* xp = Xn + (size_t)i * 256 + 4 * lane;
    ushort4 xv = *(const ushort4*)xp;
    float v0 = fmaxf(b2f(xv.x) + a0 * inv, 0.0f);
    float v1 = fmaxf(b2f(xv.y) + a1 * inv, 0.0f);
    float v2 = fmaxf(b2f(xv.z) + a2 * inv, 0.0f);
    float v3 = fmaxf(b2f(xv.w) + a3 * inv, 0.0f);
    ushort4 o;
    o.x = f2b(v0); o.y = f2b(v1); o.z = f2b(v2); o.w = f2b(v3);
    *(ushort4*)xp = o;
    if (DOT) {
        float4 wv4 = *(const float4*)(w + 4 * lane);
        float d = v0 * wv4.x + v1 * wv4.y + v2 * wv4.z + v3 * wv4.w;
        #pragma unroll
        for (int off = 32; off > 0; off >>= 1) d += __shfl_down(d, off);
        if (lane == 0) dotbuf[i] = d;
    }
}

// ---------------------------------------------------------------- pool reduce + head
__global__ void out_init_k(float* __restrict__ out, const float* __restrict__ headb) {
    int i = threadIdx.x;
    if (i < G_GRAPH * S_SAMP) out[i] = headb[0];
}

__global__ __launch_bounds__(256) void reduce_k(const float* __restrict__ dotbuf,
                                                const int* __restrict__ batch,
                                                float* __restrict__ out,
                                                int count, int s_base) {
    __shared__ float part[G_GRAPH * S_SAMP];
    if (threadIdx.x < G_GRAPH * S_SAMP) part[threadIdx.x] = 0.0f;
    __syncthreads();
    for (int i = blockIdx.x * 256 + threadIdx.x; i < count; i += gridDim.x * 256) {
        int s = s_base + ((i >= N_NODES) ? 1 : 0);
        int n = (i >= N_NODES) ? i - N_NODES : i;
        atomicAdd(&part[batch[n] * S_SAMP + s], dotbuf[i]);
    }
    __syncthreads();
    if (threadIdx.x < G_GRAPH * S_SAMP)
        atomicAdd(&out[threadIdx.x], part[threadIdx.x]);
}

// ---------------------------------------------------------------- launch
extern "C" void kernel_launch(void* const* d_in, const int* in_sizes, int n_in,
                              void* d_out, int out_size, void* d_ws, size_t ws_size,
                              hipStream_t stream) {
    const float* x_feat      = (const float*)d_in[0];
    const float* dim_feat    = (const float*)d_in[1];
    const float* layout_feat = (const float*)d_in[2];
    const float* tile_feat   = (const float*)d_in[3];
    const float* opemb       = (const float*)d_in[4];
    const float* preW        = (const float*)d_in[5];
    const float* preb        = (const float*)d_in[6];
    const float* convWl      = (const float*)d_in[7];
    const float* convWr      = (const float*)d_in[8];
    const float* convb       = (const float*)d_in[9];
    const float* revWl       = (const float*)d_in[10];
    const float* revWr       = (const float*)d_in[11];
    const float* revb        = (const float*)d_in[12];
    const float* headW       = (const float*)d_in[13];
    const float* headb       = (const float*)d_in[14];
    const int*   node_opcode = (const int*)d_in[15];
    const int*   batch       = (const int*)d_in[16];
    const int*   edge_index  = (const int*)d_in[17];
    float* out = (float*)d_out;

    const bool merged = ws_size >= (330ull << 20);   // constant per session -> graph-safe

    char* ws = (char*)d_ws;
    size_t off = 0;
    auto alloc = [&](size_t nbytes) {
        char* p = ws + off;
        off += (nbytes + 255) & ~(size_t)255;
        return p;
    };
    size_t xrows = merged ? (size_t)M2 : (size_t)NPAD;
    u16* XA   = (u16*)alloc(xrows * 256 * 2);
    u16* XB   = (u16*)alloc(xrows * 256 * 2);
    // merged: region holds A2 (NPAD*384 = 76.9MB) then H (M2*256 = 102.4MB)
    // fallback: Xin (NPAD*384) then H (NPAD*256)
    u16* A2H  = (u16*)alloc(merged ? (size_t)M2 * 256 * 2 : (size_t)NPAD * KPRE * 2);
    u16* Wt    = (u16*)alloc((size_t)NLAYER * 512 * 256 * 2);
    u16* preWt = (u16*)alloc((size_t)256 * KPRE * 2);
    u16* W2t   = (u16*)alloc((size_t)512 * KPRE * 2);
    float* bcat  = (float*)alloc(NLAYER * 512 * 4);
    float* bias2 = (float*)alloc(512 * 4);
    float* dotbuf = (float*)alloc((merged ? M2 : N_NODES) * 4);
    int* degF  = (int*)alloc(N_NODES * 4);
    int* degR  = (int*)alloc(N_NODES * 4);
    int* rpF   = (int*)alloc((N_NODES + 1) * 4);
    int* rpR   = (int*)alloc((N_NODES + 1) * 4);
    int* curF  = (int*)alloc(N_NODES * 4);
    int* curR  = (int*)alloc(N_NODES * 4);
    int* colF  = (int*)alloc(E_EDGES * 4);
    int* colR  = (int*)alloc(E_EDGES * 4);
    int* bsum  = (int*)alloc(2 * NB1 * 4);
    float* invF = (float*)alloc(N_NODES * 4);
    float* invR = (float*)alloc(N_NODES * 4);

    hipMemsetAsync(degF, 0, N_NODES * 4, stream);
    hipMemsetAsync(degR, 0, N_NODES * 4, stream);

    pack_w_k<<<(NLAYER * 512 * 256 + 255) / 256, 256, 0, stream>>>(
        convWl, revWl, convWr, revWr, convb, revb, Wt, bcat);
    deg_k<<<(E_EDGES + 255) / 256, 256, 0, stream>>>(edge_index, degF, degR);
    scan1_k<<<dim3(NB1, 2), 1024, 0, stream>>>(degF, degR, rpF, rpR, bsum);
    scan2_k<<<1, 256, 0, stream>>>(bsum, rpF, rpR);
    scan3_k<<<dim3(NB1, 2), 1024, 0, stream>>>(bsum, rpF, rpR);
    inv_cursor_k<<<(N_NODES + 255) / 256, 256, 0, stream>>>(
        degF, degR, rpF, rpR, invF, invR, curF, curR);
    fill_k<<<(E_EDGES + 255) / 256, 256, 0, stream>>>(edge_index, curF, curR, colF, colR);
    out_init_k<<<1, 64, 0, stream>>>(out, headb);

    if (merged) {
        pack_pre2_k<<<(512 * KPRE + 255) / 256, 256, 0, stream>>>(preW, preb, W2t, bias2);
        build_m_k<<<(N_NODES * 77 + 255) / 256, 256, 0, stream>>>(
            x_feat, dim_feat, layout_feat, tile_feat, opemb, node_opcode, batch, A2H);
        // [X0_s0 | X0_s1] = relu(A2 @ W2 + bias2): C0 = rows 0..N-1, C1 = rows N..2N-1
        const int gridPre = ((NRT64 + 7) / 8) * 8 * 8;   // 196*64 = 12544
        mmA_k<true, 3, 8><<<gridPre, 256, 0, stream>>>(
            A2H, W2t, bias2, XA, XA + (size_t)N_NODES * 256, N_NODES, NRT64);

        const int gridL = ((MT2 + 7) / 8) * 8 * 8;       // 391*64 = 25024
        const int gridAgg = (M2 * 64 + 255) / 256;       // 50000
        u16* ins[NLAYER]  = {XA, XB, XA, XB};
        u16* outs[NLAYER] = {XB, XA, XB, XA};
        for (int l = 0; l < NLAYER; l++) {
            mmA_k<false, 2, 8><<<gridL, 256, 0, stream>>>(
                ins[l], Wt + (size_t)l * 512 * 256, bcat + (size_t)l * 512,
                outs[l], A2H, M2, MT2);
            if (l < 2) {
                agg_k<false><<<gridAgg, 256, 0, stream>>>(
                    rpF, colF, rpR, colR, invF, invR, A2H, outs[l],
                    nullptr, nullptr, M2);
            } else {
                agg_k<true><<<gridAgg, 256, 0, stream>>>(
                    rpF, colF, rpR, colR, invF, invR, A2H, outs[l],
                    headW + (l == 2 ? 0 : 256), dotbuf, M2);
                reduce_k<<<128, 256, 0, stream>>>(dotbuf, batch, out, M2, 0);
            }
        }
    } else {
        pack_pre_k<<<(256 * KPRE + 255) / 256, 256, 0, stream>>>(preW, preWt);
        const int gridPre = ((NRT64 + 7) / 8) * 8 * 4;
        const int gridL   = ((NRT64 + 7) / 8) * 8 * 8;
        const int gridAgg = (N_NODES * 64 + 255) / 256;
        for (int s = 0; s < S_SAMP; s++) {
            build_s_k<<<(N_NODES * 67 + 255) / 256, 256, 0, stream>>>(
                x_feat, dim_feat, layout_feat, tile_feat, opemb, node_opcode,
                batch, s, A2H);
            mmA_k<true, 3, 4><<<gridPre, 256, 0, stream>>>(
                A2H, preWt, preb, XA, XA, N_NODES, NRT64);
            u16* ins[NLAYER]  = {XA, XB, XA, XB};
            u16* outs[NLAYER] = {XB, XA, XB, XA};
            for (int l = 0; l < NLAYER; l++) {
                mmA_k<false, 2, 8><<<gridL, 256, 0, stream>>>(
                    ins[l], Wt + (size_t)l * 512 * 256, bcat + (size_t)l * 512,
                    outs[l], A2H, N_NODES, NRT64);
                if (l < 2) {
                    agg_k<false><<<gridAgg, 256, 0, stream>>>(
                        rpF, colF, rpR, colR, invF, invR, A2H, outs[l],
                        nullptr, nullptr, N_NODES);
                } else {
                    agg_k<true><<<gridAgg, 256, 0, stream>>>(
                        rpF, colF, rpR, colR, invF, invR, A2H, outs[l],
                        headW + (l == 2 ? 0 : 256), dotbuf, N_NODES);
                    reduce_k<<<128, 256, 0, stream>>>(dotbuf, batch, out, N_NODES, s);
                }
            }
        }
    }
}

// Round 10
// 1408.328 us; speedup vs baseline: 1.9156x; 1.0350x over previous
//
#include <hip/hip_runtime.h>
#include <hip/hip_bf16.h>

#define N_NODES 100000
#define S_SAMP 2
#define G_GRAPH 8
#define E_EDGES 400000
#define NLAYER 4
#define IN_CH 265
#define KPRE 384                        // K padded to 3*128 chunks
#define MT128 ((N_NODES + 127) / 128)   // 782 row tiles (128 rows)
#define NPAD (MT128 * 128)              // 100096 padded rows
#define NG128 ((MT128 + 7) / 8)         // 98 groups -> 8 XCDs
#define NB1 ((N_NODES + 1023) / 1024)   // 98 scan blocks

typedef unsigned short u16;
typedef unsigned int u32;
typedef short bf16x8 __attribute__((ext_vector_type(8)));
typedef float f32x4 __attribute__((ext_vector_type(4)));

__device__ __forceinline__ float b2f(u16 u) {
    union { u32 i; float f; } x; x.i = ((u32)u) << 16; return x.f;
}
__device__ __forceinline__ u16 f2b(float f) {
    __hip_bfloat16 h = __float2bfloat16(f);
    return *reinterpret_cast<u16*>(&h);
}

// async global->LDS, 16B per lane; lds dest = wave-uniform base + lane*16
__device__ __forceinline__ void gl_lds16(const u16* g, u16* l) {
    __builtin_amdgcn_global_load_lds(
        (const __attribute__((address_space(1))) void*)g,
        (__attribute__((address_space(3))) void*)l, 16, 0, 0);
}

// ---------------------------------------------------------------- features (per s)
// xin[n][384] = [x(53)|op(32)|dim(138)|lay_s(24)|tile_s(18)|pad]; ushort4 stores
__global__ __launch_bounds__(256) void build_s_k(const float* __restrict__ xf,
                                                 const float* __restrict__ dimf,
                                                 const float* __restrict__ layf,
                                                 const float* __restrict__ tilef,
                                                 const float* __restrict__ opemb,
                                                 const int* __restrict__ opcode,
                                                 const int* __restrict__ batch,
                                                 int s, u16* __restrict__ xin) {
    int item = blockIdx.x * blockDim.x + threadIdx.x;
    int n = item / 67;
    if (n >= N_NODES) return;
    int base = (item - n * 67) * 4;
    int opc = opcode[n];
    int g = batch[n];
    ushort4 o;
    u16* op = &o.x;
    #pragma unroll
    for (int u = 0; u < 4; u++) {
        int c = base + u;
        float v = 0.0f;
        if (c < 53)       v = xf[(size_t)n * 53 + c];
        else if (c < 85)  v = opemb[opc * 32 + (c - 53)];
        else if (c < 223) v = dimf[(size_t)n * 138 + (c - 85)];
        else if (c < 247) v = layf[((size_t)n * 2 + s) * 24 + (c - 223)];
        else if (c < 265) v = tilef[((size_t)g * 2 + s) * 18 + (c - 247)];
        op[u] = f2b(v);
    }
    *(ushort4*)(xin + (size_t)n * KPRE + base) = o;
}

// ---------------------------------------------------------------- weight packing
// Wt: [L][512][256] bf16 transposed.  col<256 -> Wr_cat (P), col>=256 -> Wl_cat (H).
__global__ void pack_w_k(const float* __restrict__ cWl, const float* __restrict__ rWl,
                         const float* __restrict__ cWr, const float* __restrict__ rWr,
                         const float* __restrict__ cb,  const float* __restrict__ rb,
                         u16* __restrict__ Wt, float* __restrict__ bcat) {
    int idx = blockIdx.x * blockDim.x + threadIdx.x;
    if (idx < NLAYER * 512 * 256) {
        int l = idx >> 17;
        int r = idx & 131071;
        int j = r >> 8;
        int k = r & 255;
        int jj = j & 255;
        int half = j >> 8;
        int sub = jj >> 7;
        int col = jj & 127;
        const float* src = half ? (sub ? rWl : cWl) : (sub ? rWr : cWr);
        Wt[idx] = f2b(src[((size_t)l * 256 + k) * 128 + col]);
    }
    if (idx < NLAYER * 512) {
        int l = idx >> 9;
        int j = idx & 511;
        float v = 0.0f;
        if (j < 256) v = (j < 128) ? cb[l * 128 + j] : rb[l * 128 + (j - 128)];
        bcat[idx] = v;
    }
}

// preWt [256][384] transposed, zero-padded K
__global__ void pack_pre_k(const float* __restrict__ preW, u16* __restrict__ preWt) {
    int idx = blockIdx.x * blockDim.x + threadIdx.x;
    if (idx >= 256 * KPRE) return;
    int j = idx / KPRE;
    int k = idx - j * KPRE;
    preWt[idx] = (k < IN_CH) ? f2b(preW[(size_t)k * 256 + j]) : (u16)0;
}

// ---------------------------------------------------------------- degrees + CSR
__global__ void deg_k(const int* __restrict__ ei, int* __restrict__ degF,
                      int* __restrict__ degR) {
    int e = blockIdx.x * blockDim.x + threadIdx.x;
    if (e < E_EDGES) {
        atomicAdd(&degF[ei[E_EDGES + e]], 1);
        atomicAdd(&degR[ei[e]], 1);
    }
}

__global__ __launch_bounds__(1024) void scan1_k(const int* __restrict__ degF,
                                                const int* __restrict__ degR,
                                                int* __restrict__ rpF,
                                                int* __restrict__ rpR,
                                                int* __restrict__ bsum) {
    const int* deg = blockIdx.y ? degR : degF;
    int* rp = blockIdx.y ? rpR : rpF;
    __shared__ int buf[1024];
    int i = blockIdx.x * 1024 + threadIdx.x;
    int v = (i < N_NODES) ? deg[i] : 0;
    buf[threadIdx.x] = v;
    __syncthreads();
    for (int off = 1; off < 1024; off <<= 1) {
        int t = (threadIdx.x >= off) ? buf[threadIdx.x - off] : 0;
        __syncthreads();
        buf[threadIdx.x] += t;
        __syncthreads();
    }
    if (i < N_NODES) rp[i] = buf[threadIdx.x] - v;
    if (threadIdx.x == 1023) bsum[blockIdx.y * NB1 + blockIdx.x] = buf[1023];
}

__global__ __launch_bounds__(256) void scan2_k(int* __restrict__ bsum,
                                               int* __restrict__ rpF,
                                               int* __restrict__ rpR) {
    __shared__ int buf[2][128];
    int half = threadIdx.x >> 7;
    int t = threadIdx.x & 127;
    int v = (t < NB1) ? bsum[half * NB1 + t] : 0;
    buf[half][t] = v;
    __syncthreads();
    for (int off = 1; off < 128; off <<= 1) {
        int x = (t >= off) ? buf[half][t - off] : 0;
        __syncthreads();
        buf[half][t] += x;
        __syncthreads();
    }
    if (t < NB1) bsum[half * NB1 + t] = buf[half][t] - v;
    if (t == NB1) (half ? rpR : rpF)[N_NODES] = buf[half][NB1 - 1];
}

__global__ void scan3_k(const int* __restrict__ bsum, int* __restrict__ rpF,
                        int* __restrict__ rpR) {
    int* rp = blockIdx.y ? rpR : rpF;
    int i = blockIdx.x * 1024 + threadIdx.x;
    if (i < N_NODES) rp[i] += bsum[blockIdx.y * NB1 + blockIdx.x];
}

__global__ void inv_cursor_k(const int* __restrict__ degF, const int* __restrict__ degR,
                             const int* __restrict__ rpF, const int* __restrict__ rpR,
                             float* __restrict__ invF, float* __restrict__ invR,
                             int* __restrict__ curF, int* __restrict__ curR) {
    int i = blockIdx.x * blockDim.x + threadIdx.x;
    if (i < N_NODES) {
        invF[i] = 1.0f / fmaxf((float)degF[i], 1.0f);
        invR[i] = 1.0f / fmaxf((float)degR[i], 1.0f);
        curF[i] = rpF[i];
        curR[i] = rpR[i];
    }
}

__global__ void fill_k(const int* __restrict__ ei, int* __restrict__ curF,
                       int* __restrict__ curR, int* __restrict__ colF,
                       int* __restrict__ colR) {
    int e = blockIdx.x * blockDim.x + threadIdx.x;
    if (e < E_EDGES) {
        int s = ei[e], t = ei[E_EDGES + e];
        colF[atomicAdd(&curF[t], 1)] = s;
        colR[atomicAdd(&curR[s], 1)] = t;
    }
}

// ---------------------------------------------------------------- MFMA GEMM (128x64 tile, DMA-staged)
// Block: 128 rows x 64 cols. 4 waves; wave w = rows [w*32, w*32+32) x 64 cols.
// K = NCHUNK*128 in chunks via global_load_lds (16B/lane), XOR slot swizzle.
// LDS 48 KB (A 32 + B 16) -> 3 blocks/CU. Per chunk per wave: 12 DMA, 32 MFMA.
// Global col<256 -> C0 (+bias), else C1. XCD swizzle: bid = g*(8*COLT)+c*8+x.
template <bool RELU_OUT, int NCHUNK, int COLT>
__global__ __launch_bounds__(256) void mmB_k(const u16* __restrict__ A,
                                             const u16* __restrict__ Bt,
                                             const float* __restrict__ bias,
                                             u16* __restrict__ C0,
                                             u16* __restrict__ C1,
                                             int M) {
    __shared__ u16 As[128 * 128];    // 32 KB
    __shared__ u16 Bs[64 * 128];     // 16 KB
    constexpr int K = NCHUNK * 128;

    int bid = blockIdx.x;
    int x = bid & 7;
    int q = bid >> 3;
    int c = q % COLT;
    int g = q / COLT;
    int rowTile = g * 8 + x;
    if (rowTile >= MT128) return;
    int rowBase = rowTile * 128;
    int colBase = c * 64;

    int tid = threadIdx.x;
    int wv = tid >> 6;
    int lane = tid & 63;
    int quad = lane >> 4;
    int l16 = lane & 15;
    int rsub = lane >> 4;
    int sl = lane & 15;

    f32x4 acc[2][4] = {};

    for (int ci = 0; ci < NCHUNK; ci++) {
        int k0 = ci * 128;
        // A: wave wv stages rows [wv*32, wv*32+32): 8 DMA instrs x 4 rows
        #pragma unroll
        for (int i = 0; i < 8; i++) {
            int r = wv * 32 + 4 * i + rsub;
            int ch = sl ^ (r & 15);
            gl_lds16(A + (size_t)(rowBase + r) * K + k0 + ch * 8,
                     As + (wv * 32 + 4 * i) * 128);
        }
        // B: wave wv stages rows [wv*16, wv*16+16): 4 DMA instrs
        #pragma unroll
        for (int i = 0; i < 4; i++) {
            int r = wv * 16 + 4 * i + rsub;
            int ch = sl ^ (r & 15);
            gl_lds16(Bt + (size_t)(colBase + r) * K + k0 + ch * 8,
                     Bs + (wv * 16 + 4 * i) * 128);
        }
        __syncthreads();
        #pragma unroll
        for (int ks = 0; ks < 4; ks++) {
            int ca = ks * 4 + quad;
            bf16x8 af[2];
            #pragma unroll
            for (int rf = 0; rf < 2; rf++) {
                int ra = wv * 32 + rf * 16 + l16;
                af[rf] = *(const bf16x8*)(As + ra * 128 + (ca ^ (ra & 15)) * 8);
            }
            #pragma unroll
            for (int cf = 0; cf < 4; cf++) {
                int rb = cf * 16 + l16;
                bf16x8 bf = *(const bf16x8*)(Bs + rb * 128 + (ca ^ (rb & 15)) * 8);
                acc[0][cf] = __builtin_amdgcn_mfma_f32_16x16x32_bf16(af[0], bf, acc[0][cf], 0, 0, 0);
                acc[1][cf] = __builtin_amdgcn_mfma_f32_16x16x32_bf16(af[1], bf, acc[1][cf], 0, 0, 0);
            }
        }
        if (ci + 1 < NCHUNK) __syncthreads();
    }

    // epilogue: C/D layout col=lane&15, row=quad*4+reg
    u16* dst = (colBase < 256) ? C0 : C1;
    int cb = colBase & 255;
    #pragma unroll
    for (int rf = 0; rf < 2; rf++) {
        #pragma unroll
        for (int cf = 0; cf < 4; cf++) {
            int col = cb + cf * 16 + l16;
            float bv = bias[colBase + cf * 16 + l16];
            #pragma unroll
            for (int r = 0; r < 4; r++) {
                int row = rowBase + wv * 32 + rf * 16 + quad * 4 + r;
                if (row < M) {
                    float v = acc[rf][cf][r] + bv;
                    if (RELU_OUT) v = fmaxf(v, 0.0f);
                    dst[(size_t)row * 256 + col] = f2b(v);
                }
            }
        }
    }
}

// ---------------------------------------------------------------- aggregation (CSR gather)
// One wave per node. Lanes 0-31: fwd half (H[.,0:128]); lanes 32-63: rev half.
// X := relu(X + inv*gather). If DOT: dotbuf[n] = X_new . w.
template <bool DOT>
__global__ __launch_bounds__(256) void agg_k(const int* __restrict__ rpF,
                                             const int* __restrict__ colF,
                                             const int* __restrict__ rpR,
                                             const int* __restrict__ colR,
                                             const float* __restrict__ invF,
                                             const float* __restrict__ invR,
                                             const u16* __restrict__ H,
                                             u16* __restrict__ Xn,
                                             const float* __restrict__ w,
                                             float* __restrict__ dotbuf) {
    int n = (blockIdx.x * blockDim.x + threadIdx.x) >> 6;
    if (n >= N_NODES) return;
    int lane = threadIdx.x & 63;
    int half = lane >> 5;
    int l32 = lane & 31;
    const int* rp  = half ? rpR : rpF;
    const int* col = half ? colR : colF;
    float inv = half ? invR[n] : invF[n];
    const u16* Hb = H + half * 128 + 4 * l32;

    float a0 = 0, a1 = 0, a2 = 0, a3 = 0;
    int b = rp[n], e = rp[n + 1];
    int j = b;
    for (; j + 7 < e; j += 8) {
        int c0 = col[j],     c1 = col[j + 1], c2 = col[j + 2], c3 = col[j + 3];
        int c4 = col[j + 4], c5 = col[j + 5], c6 = col[j + 6], c7 = col[j + 7];
        ushort4 h0 = *(const ushort4*)(Hb + (size_t)c0 * 256);
        ushort4 h1 = *(const ushort4*)(Hb + (size_t)c1 * 256);
        ushort4 h2 = *(const ushort4*)(Hb + (size_t)c2 * 256);
        ushort4 h3 = *(const ushort4*)(Hb + (size_t)c3 * 256);
        ushort4 h4 = *(const ushort4*)(Hb + (size_t)c4 * 256);
        ushort4 h5 = *(const ushort4*)(Hb + (size_t)c5 * 256);
        ushort4 h6 = *(const ushort4*)(Hb + (size_t)c6 * 256);
        ushort4 h7 = *(const ushort4*)(Hb + (size_t)c7 * 256);
        a0 += b2f(h0.x) + b2f(h1.x) + b2f(h2.x) + b2f(h3.x)
            + b2f(h4.x) + b2f(h5.x) + b2f(h6.x) + b2f(h7.x);
        a1 += b2f(h0.y) + b2f(h1.y) + b2f(h2.y) + b2f(h3.y)
            + b2f(h4.y) + b2f(h5.y) + b2f(h6.y) + b2f(h7.y);
        a2 += b2f(h0.z) + b2f(h1.z) + b2f(h2.z) + b2f(h3.z)
            + b2f(h4.z) + b2f(h5.z) + b2f(h6.z) + b2f(h7.z);
        a3 += b2f(h0.w) + b2f(h1.w) + b2f(h2.w) + b2f(h3.w)
            + b2f(h4.w) + b2f(h5.w) + b2f(h6.w) + b2f(h7.w);
    }
    for (; j + 3 < e; j += 4) {
        int c0 = col[j], c1 = col[j + 1], c2 = col[j + 2], c3 = col[j + 3];
        ushort4 h0 = *(const ushort4*)(Hb + (size_t)c0 * 256);
        ushort4 h1 = *(const ushort4*)(Hb + (size_t)c1 * 256);
        ushort4 h2 = *(const ushort4*)(Hb + (size_t)c2 * 256);
        ushort4 h3 = *(const ushort4*)(Hb + (size_t)c3 * 256);
        a0 += b2f(h0.x) + b2f(h1.x) + b2f(h2.x) + b2f(h3.x);
        a1 += b2f(h0.y) + b2f(h1.y) + b2f(h2.y) + b2f(h3.y);
        a2 += b2f(h0.z) + b2f(h1.z) + b2f(h2.z) + b2f(h3.z);
        a3 += b2f(h0.w) + b2f(h1.w) + b2f(h2.w) + b2f(h3.w);
    }
    for (; j < e; j++) {
        int c = col[j];
        ushort4 h = *(const ushort4*)(Hb + (size_t)c * 256);
        a0 += b2f(h.x); a1 += b2f(h.y); a2 += b2f(h.z); a3 += b2f(h.w);
    }
    u16* xp = Xn + (size_t)n * 256 + 4 * lane;
    ushort4 xv = *(const ushort4*)xp;
    float v0 = fmaxf(b2f(xv.x) + a0 * inv, 0.0f);
    float v1 = fmaxf(b2f(xv.y) + a1 * inv, 0.0f);
    float v2 = fmaxf(b2f(xv.z) + a2 * inv, 0.0f);
    float v3 = fmaxf(b2f(xv.w) + a3 * inv, 0.0f);
    ushort4 o;
    o.x = f2b(v0); o.y = f2b(v1); o.z = f2b(v2); o.w = f2b(v3);
    *(ushort4*)xp = o;
    if (DOT) {
        float4 wv4 = *(const float4*)(w + 4 * lane);
        float d = v0 * wv4.x + v1 * wv4.y + v2 * wv4.z + v3 * wv4.w;
        #pragma unroll
        for (int off = 32; off > 0; off >>= 1) d += __shfl_down(d, off);
        if (lane == 0) dotbuf[n] = d;
    }
}

// ---------------------------------------------------------------- pool reduce + head
__global__ void out_init_k(float* __restrict__ out, const float* __restrict__ headb) {
    int i = threadIdx.x;
    if (i < G_GRAPH * S_SAMP) out[i] = headb[0];
}

__global__ __launch_bounds__(256) void reduce_k(const float* __restrict__ dotbuf,
                                                const int* __restrict__ batch,
                                                float* __restrict__ out, int s) {
    __shared__ float part[G_GRAPH];
    if (threadIdx.x < G_GRAPH) part[threadIdx.x] = 0.0f;
    __syncthreads();
    for (int i = blockIdx.x * 256 + threadIdx.x; i < N_NODES; i += gridDim.x * 256)
        atomicAdd(&part[batch[i]], dotbuf[i]);
    __syncthreads();
    if (threadIdx.x < G_GRAPH)
        atomicAdd(&out[threadIdx.x * S_SAMP + s], part[threadIdx.x]);
}

// ---------------------------------------------------------------- launch
extern "C" void kernel_launch(void* const* d_in, const int* in_sizes, int n_in,
                              void* d_out, int out_size, void* d_ws, size_t ws_size,
                              hipStream_t stream) {
    const float* x_feat      = (const float*)d_in[0];
    const float* dim_feat    = (const float*)d_in[1];
    const float* layout_feat = (const float*)d_in[2];
    const float* tile_feat   = (const float*)d_in[3];
    const float* opemb       = (const float*)d_in[4];
    const float* preW        = (const float*)d_in[5];
    const float* preb        = (const float*)d_in[6];
    const float* convWl      = (const float*)d_in[7];
    const float* convWr      = (const float*)d_in[8];
    const float* convb       = (const float*)d_in[9];
    const float* revWl       = (const float*)d_in[10];
    const float* revWr       = (const float*)d_in[11];
    const float* revb        = (const float*)d_in[12];
    const float* headW       = (const float*)d_in[13];
    const float* headb       = (const float*)d_in[14];
    const int*   node_opcode = (const int*)d_in[15];
    const int*   batch       = (const int*)d_in[16];
    const int*   edge_index  = (const int*)d_in[17];
    float* out = (float*)d_out;

    char* ws = (char*)d_ws;
    size_t off = 0;
    auto alloc = [&](size_t nbytes) {
        char* p = ws + off;
        off += (nbytes + 255) & ~(size_t)255;
        return p;
    };
    u16* XA    = (u16*)alloc((size_t)NPAD * 256 * 2);      // 51.25 MB
    u16* XB    = (u16*)alloc((size_t)NPAD * 256 * 2);
    u16* XinH  = (u16*)alloc((size_t)NPAD * KPRE * 2);     // Xin (K=384), reused as H
    u16* Wt    = (u16*)alloc((size_t)NLAYER * 512 * 256 * 2);
    u16* preWt = (u16*)alloc((size_t)256 * KPRE * 2);
    float* bcat   = (float*)alloc(NLAYER * 512 * 4);
    float* dotbuf = (float*)alloc((size_t)N_NODES * 4);
    int* degF  = (int*)alloc(N_NODES * 4);
    int* degR  = (int*)alloc(N_NODES * 4);
    int* rpF   = (int*)alloc((N_NODES + 1) * 4);
    int* rpR   = (int*)alloc((N_NODES + 1) * 4);
    int* curF  = (int*)alloc(N_NODES * 4);
    int* curR  = (int*)alloc(N_NODES * 4);
    int* colF  = (int*)alloc(E_EDGES * 4);
    int* colR  = (int*)alloc(E_EDGES * 4);
    int* bsum  = (int*)alloc(2 * NB1 * 4);
    float* invF = (float*)alloc(N_NODES * 4);
    float* invR = (float*)alloc(N_NODES * 4);

    hipMemsetAsync(degF, 0, N_NODES * 4, stream);
    hipMemsetAsync(degR, 0, N_NODES * 4, stream);

    pack_w_k<<<(NLAYER * 512 * 256 + 255) / 256, 256, 0, stream>>>(
        convWl, revWl, convWr, revWr, convb, revb, Wt, bcat);
    pack_pre_k<<<(256 * KPRE + 255) / 256, 256, 0, stream>>>(preW, preWt);
    deg_k<<<(E_EDGES + 255) / 256, 256, 0, stream>>>(edge_index, degF, degR);
    scan1_k<<<dim3(NB1, 2), 1024, 0, stream>>>(degF, degR, rpF, rpR, bsum);
    scan2_k<<<1, 256, 0, stream>>>(bsum, rpF, rpR);
    scan3_k<<<dim3(NB1, 2), 1024, 0, stream>>>(bsum, rpF, rpR);
    inv_cursor_k<<<(N_NODES + 255) / 256, 256, 0, stream>>>(
        degF, degR, rpF, rpR, invF, invR, curF, curR);
    fill_k<<<(E_EDGES + 255) / 256, 256, 0, stream>>>(edge_index, curF, curR, colF, colR);
    out_init_k<<<1, 64, 0, stream>>>(out, headb);

    const int gridPre = NG128 * 8 * 4;   // 3136
    const int gridL   = NG128 * 8 * 8;   // 6272
    const int gridAgg = (N_NODES * 64 + 255) / 256;

    for (int s = 0; s < S_SAMP; s++) {
        build_s_k<<<(N_NODES * 67 + 255) / 256, 256, 0, stream>>>(
            x_feat, dim_feat, layout_feat, tile_feat, opemb, node_opcode,
            batch, s, XinH);
        // X0 = relu(Xin @ preW + preb); K=384 = 3 chunks
        mmB_k<true, 3, 4><<<gridPre, 256, 0, stream>>>(
            XinH, preWt, preb, XA, XA, N_NODES);

        u16* ins[NLAYER]  = {XA, XB, XA, XB};
        u16* outs[NLAYER] = {XB, XA, XB, XA};
        for (int l = 0; l < NLAYER; l++) {
            // fused: [P | H] = x~ @ [Wr_cat | Wl_cat] + [b_cat | 0]; K=256 = 2 chunks
            mmB_k<false, 2, 8><<<gridL, 256, 0, stream>>>(
                ins[l], Wt + (size_t)l * 512 * 256, bcat + (size_t)l * 512,
                outs[l], XinH, N_NODES);
            if (l < 2) {
                agg_k<false><<<gridAgg, 256, 0, stream>>>(
                    rpF, colF, rpR, colR, invF, invR, XinH, outs[l],
                    nullptr, nullptr);
            } else {
                agg_k<true><<<gridAgg, 256, 0, stream>>>(
                    rpF, colF, rpR, colR, invF, invR, XinH, outs[l],
                    headW + (l == 2 ? 0 : 256), dotbuf);
                reduce_k<<<128, 256, 0, stream>>>(dotbuf, batch, out, s);
            }
        }
    }
}